// Round 15
// baseline (150.948 us; speedup 1.0000x reference)
//
#include <hip/hip_runtime.h>
#include <math.h>

#define MAX_ITER 20
#define NROUND (MAX_ITER / 2)
#define EPS_W 1e-3f
#define CLAMP_MIN 1e-4f
#define CLAMP_MAX 1e4f

#define E 16
#define CGBLK 256
#define CHUNK (E * CGBLK)  // 4096 elems/block; bpb = K/CHUNK = 32
#define SPAN_MAX 8960      // block i-span bound (mean 8192, sd ~90; ~8.5 sigma; slow-path fallback beyond)
#define PAD(t) ((t) + ((t) >> 5))
#define SPAN_PAD (SPAN_MAX + SPAN_MAX / 32)  // 9240

// Per-block 1KB slot line; words within:
#define SLOT_STRIDE 128
#define PW_AB 0    // (a|d)
#define PW_EF 1    // (e|f)
#define PW_GH 2    // (g|h)
#define PW_KL 3    // (k|l)
#define PW_RS0 4   // (rs0|-) at t==0
#define PW_L0 5    // left edge (kp0|kp1)   [init: (dg0|cl1)]
#define PW_L1 6    // (kr0|kr1)             [init: (r0|r1)]
#define PW_L2 7    // (k2p0|k2p1)
#define PW_R0 8    // right edge (kpE-2|kpE-1) [init: (dgE-1|clE-1)]
#define PW_R1 9    // (krE-2|krE-1)            [init: (rE-2|rE-1)]
#define PW_R2 10   // (k2pE-2|k2pE-1)
#define PW_TAG 11  // release-stored {gen|0}
#define PW_V0 12   // epilogue, self-tagged
#define PW_PHI 13  // epilogue, self-tagged

__device__ __forceinline__ float sp_w(float u) {
    float sp = fmaxf(u, 0.f) + log1pf(expf(-fabsf(u)));
    float w = sp + EPS_W;
    return fminf(fmaxf(w, CLAMP_MIN), CLAMP_MAX);
}
__device__ __forceinline__ float nn(float x) { return (x == x) ? x : 0.f; }

// SYSTEM-scope atomics: cache-bypassing, coherence-point direct (r6->r7: 21us->3.4us/round)
__device__ __forceinline__ unsigned long long sys_ld64(const unsigned long long* p) {
    return __hip_atomic_load(p, __ATOMIC_RELAXED, __HIP_MEMORY_SCOPE_SYSTEM);
}
__device__ __forceinline__ unsigned long long sys_ld64_acq(const unsigned long long* p) {
    return __hip_atomic_load(p, __ATOMIC_ACQUIRE, __HIP_MEMORY_SCOPE_SYSTEM);
}
__device__ __forceinline__ void sys_st64(unsigned long long* p, unsigned long long v) {
    __hip_atomic_store(p, v, __ATOMIC_RELAXED, __HIP_MEMORY_SCOPE_SYSTEM);
}
__device__ __forceinline__ void sys_st64_rel(unsigned long long* p, unsigned long long v) {
    __hip_atomic_store(p, v, __ATOMIC_RELEASE, __HIP_MEMORY_SCOPE_SYSTEM);
}
__device__ __forceinline__ unsigned long long poll_tag(const unsigned long long* p, unsigned gen) {
    unsigned long long v; int s = 0;
    for (;;) {
        v = sys_ld64(p);
        if ((unsigned)(v >> 32) >= gen) return v;
        if ((++s & 63) == 0) {
            v = sys_ld64_acq(p);
            if ((unsigned)(v >> 32) >= gen) return v;
        }
        __builtin_amdgcn_s_sleep(1);
    }
}
__device__ __forceinline__ unsigned long long mkword(unsigned gen, float f) {
    return ((unsigned long long)gen << 32) | (unsigned long long)__float_as_uint(f);
}
__device__ __forceinline__ float payload(unsigned long long v) { return __uint_as_float((unsigned)v); }
__device__ __forceinline__ unsigned long long pack2(float a, float b) {
    return ((unsigned long long)__float_as_uint(b) << 32) | (unsigned long long)__float_as_uint(a);
}
__device__ __forceinline__ float lo2(unsigned long long v) { return __uint_as_float((unsigned)v); }
__device__ __forceinline__ float hi2(unsigned long long v) { return __uint_as_float((unsigned)(v >> 32)); }

// valid on tid 0 only
__device__ __forceinline__ float blockReduceSum(float v) {
    #pragma unroll
    for (int off = 32; off > 0; off >>= 1) v += __shfl_down(v, off, 64);
    __shared__ float smem[4];
    int lane = threadIdx.x & 63, wid = threadIdx.x >> 6;
    if (lane == 0) smem[wid] = v;
    __syncthreads();
    float r = 0.f;
    if (threadIdx.x == 0) r = smem[0] + smem[1] + smem[2] + smem[3];
    return r;
}

// CA-CG(2) persistent kernel: 2 CG iterations per communication round.
// Plain launch; co-residency by capacity: waves_per_eu(2,2) + <80KB LDS ->
// 2 blocks/CU, grid 512 = 2 x 256 CU (spin rounds proven r5-r14).
__global__ __attribute__((amdgpu_flat_work_group_size(256, 256),
                          amdgpu_waves_per_eu(2, 2)))
void k_cg_pers(const int* __restrict__ idx, const float* __restrict__ u_all,
               const float* __restrict__ x, float* __restrict__ v_out,
               float* __restrict__ w_out, float* __restrict__ r_out,
               float* __restrict__ phi,
               unsigned long long* __restrict__ slot,   // [2][nblk][SLOT_STRIDE]
               int n, int K, int B, int nblk) {
    const int blk = blockIdx.x, tid = threadIdx.x;
    const int bpb = K / CHUNK;                  // 32
    const int b = blk / bpb, bbase = b * bpb;
    const bool first = (blk == bbase), last = (blk == bbase + bpb - 1);
    const int k0 = (blk - bbase) * CHUNK + tid * E;
    const int m = n - 1;
    const float* ub = u_all + (size_t)b * m;
    const float* xb = x + (size_t)b * n;

    auto LINE = [&](int par, int blk_) -> unsigned long long* {
        return slot + ((size_t)par * nblk + blk_) * SLOT_STRIDE;
    };

    __shared__ float sX[SPAN_PAD], sW[SPAN_PAD];
    __shared__ float sEa[CGBLK], sEb[CGBLK], sEc[CGBLK], sEd[CGBLK];
    __shared__ float sred[4][8];
    __shared__ float sm[12];
    __shared__ int sInfo[4];
    __shared__ float sVN;
    __shared__ float eLb[32][6], eRb[32][6];

    // ---- span + coalesced staging ----
    if (tid == 0) {
        int kblk = (blk - bbase) * CHUNK;
        int jlo = first ? 0 : idx[kblk];
        int jhi = last ? n : idx[kblk + CHUNK];
        int lo_ = (jlo > 0) ? jlo - 1 : 0;
        sInfo[0] = lo_; sInfo[1] = jhi - lo_; sInfo[2] = jlo; sInfo[3] = jhi;
    }
    __syncthreads();
    const int lo = sInfo[0], len = sInfo[1], jloB = sInfo[2], jhiB = sInfo[3];
    const bool staged = (len <= SPAN_MAX);
    if (staged) {
        for (int t = tid; t < len; t += CGBLK) {
            int i = lo + t;
            sX[PAD(t)] = nn(xb[i]);
            sW[PAD(t)] = (i < m) ? sp_w(ub[i]) : 0.f;
        }
        __syncthreads();
    }
    auto LXn = [&](int i) -> float { return staged ? sX[PAD(i - lo)] : nn(xb[i]); };
    auto LW  = [&](int i) -> float { return staged ? sW[PAD(i - lo)] : sp_w(ub[i]); };

    // ---- init: dg, cl, r0 ----
    int jj[E + 2];
    {
        const int4* ip = reinterpret_cast<const int4*>(idx + k0);
        #pragma unroll
        for (int q4 = 0; q4 < E / 4; ++q4) {
            int4 t4 = ip[q4];
            jj[1 + 4 * q4] = t4.x; jj[2 + 4 * q4] = t4.y;
            jj[3 + 4 * q4] = t4.z; jj[4 + 4 * q4] = t4.w;
        }
        jj[0]     = (k0 > 0)     ? idx[k0 - 1] : -1000000;
        jj[E + 1] = (k0 + E < K) ? idx[k0 + E] : -1000000;
    }
    float vv[E], r[E], p[E], dgr[E], clr[E + 1];
    float s0 = 0.f;
    #pragma unroll
    for (int q = 0; q < E; ++q) {
        int j = jj[q + 1];
        bool la = (jj[q] == j - 1);
        bool ra = (jj[q + 2] == j + 1);
        float wl = 0.f, wr = 0.f;
        if (j >= 1)     { float w = LW(j - 1); wl = w * w; }
        if (j <= n - 2) { float w = LW(j);     wr = w * w; }
        float rhs = 0.f;
        if (j >= 1 && !la)     rhs += wl * LXn(j - 1);
        if (j <= n - 2 && !ra) rhs += wr * LXn(j + 1);
        vv[q] = 0.f; r[q] = rhs; p[q] = 0.f;
        dgr[q] = wl + wr;
        clr[q] = la ? wl : 0.f;
        s0 += rhs * rhs;
    }
    {
        float cl8 = 0.f;
        int j8 = jj[E + 1];
        if ((k0 + E) < K && jj[E] == j8 - 1) { float w = LW(j8 - 1); cl8 = w * w; }
        clr[E] = cl8;
    }

    // ---- init publish: statics + r0 edge pairs (parity-1 line, tag 1) ----
    {
        unsigned long long* L1 = LINE(1, blk);
        if (tid == 0) {
            sys_st64(L1 + PW_L0, pack2(dgr[0], clr[1]));
            sys_st64(L1 + PW_L1, pack2(r[0], r[1]));
        }
        if (tid == CGBLK - 1) {
            sys_st64(L1 + PW_R0, pack2(dgr[E - 1], clr[E - 1]));
            sys_st64(L1 + PW_R1, pack2(r[E - 2], r[E - 1]));
        }
    }
    float s0b = blockReduceSum(s0);   // barrier drains the stores above
    if (tid == 0) sys_st64_rel(LINE(1, blk) + PW_TAG, mkword(1u, 0.f));

    // ---- init poll: neighbor statics + r0 edges (mirror init) ----
    float dgnL = 0.f, clnL = 0.f, dgnR = 0.f, clnR = 0.f;
    float p_nb0 = 0.f, p_nb1 = 0.f, r_nb0 = 0.f, r_nb1 = 0.f;
    if (tid == 0 && !first) {
        poll_tag(LINE(1, blk - 1) + PW_TAG, 1u);
        unsigned long long s1 = sys_ld64(LINE(1, blk - 1) + PW_R0);
        unsigned long long s2 = sys_ld64(LINE(1, blk - 1) + PW_R1);
        dgnL = lo2(s1); clnL = hi2(s1); r_nb0 = lo2(s2); r_nb1 = hi2(s2);
    }
    if (tid == CGBLK - 1 && !last) {
        poll_tag(LINE(1, blk + 1) + PW_TAG, 1u);
        unsigned long long s1 = sys_ld64(LINE(1, blk + 1) + PW_L0);
        unsigned long long s2 = sys_ld64(LINE(1, blk + 1) + PW_L1);
        dgnR = lo2(s1); clnR = hi2(s1); r_nb0 = lo2(s2); r_nb1 = hi2(s2);
    }

    float rs = 0.f, beta = 0.f;

    for (int t = 0; t < NROUND; ++t) {
        const unsigned G = (unsigned)(t + 2);
        const int par = t & 1;
        unsigned long long* LP = LINE(par, blk);
        float kp[E], kr[E], k2p[E];

        // p = r + beta*p (+ mirror)
        #pragma unroll
        for (int q = 0; q < E; ++q) p[q] = r[q] + beta * p[q];
        if (tid == 0 || tid == CGBLK - 1) {
            p_nb0 = r_nb0 + beta * p_nb0;
            p_nb1 = r_nb1 + beta * p_nb1;
        }
        // exchange p,r thread edges
        sEa[tid] = p[0]; sEb[tid] = p[E - 1]; sEc[tid] = r[0]; sEd[tid] = r[E - 1];
        __syncthreads();
        float pL = (tid > 0) ? sEb[tid - 1] : (first ? 0.f : p_nb1);
        float pR = (tid < CGBLK - 1) ? sEa[tid + 1] : (last ? 0.f : p_nb0);
        float rL = (tid > 0) ? sEd[tid - 1] : (first ? 0.f : r_nb1);
        float rR = (tid < CGBLK - 1) ? sEc[tid + 1] : (last ? 0.f : r_nb0);
        // kp = K p
        #pragma unroll
        for (int q = 0; q < E; ++q) {
            float pm = (q == 0) ? pL : p[q - 1];
            float pp = (q == E - 1) ? pR : p[q + 1];
            kp[q] = dgr[q] * p[q] - clr[q] * pm - clr[q + 1] * pp;
        }
        // kp at block-adjacent neighbor position (for K^2 p at block edge)
        float kpE = 0.f;
        if (tid == 0 && !first)
            kpE = dgnL * p_nb1 - clnL * p_nb0 - clr[0] * p[0];
        if (tid == CGBLK - 1 && !last)
            kpE = dgnR * p_nb0 - clr[E] * p[E - 1] - clnR * p_nb1;
        __syncthreads();   // all reads of sEa..sEd done
        sEa[tid] = kp[0]; sEb[tid] = kp[E - 1];
        __syncthreads();
        float kpL = (tid > 0) ? sEb[tid - 1] : (first ? 0.f : kpE);
        float kpR = (tid < CGBLK - 1) ? sEa[tid + 1] : (last ? 0.f : kpE);
        // k2p = K kp ; kr = K r ; 8 Gram dots
        float dots[8] = {0.f, 0.f, 0.f, 0.f, 0.f, 0.f, 0.f, 0.f};
        #pragma unroll
        for (int q = 0; q < E; ++q) {
            float km = (q == 0) ? kpL : kp[q - 1];
            float kpp = (q == E - 1) ? kpR : kp[q + 1];
            k2p[q] = dgr[q] * kp[q] - clr[q] * km - clr[q + 1] * kpp;
            float rm = (q == 0) ? rL : r[q - 1];
            float rp = (q == E - 1) ? rR : r[q + 1];
            kr[q] = dgr[q] * r[q] - clr[q] * rm - clr[q + 1] * rp;
            dots[0] += p[q] * kp[q];
            dots[1] += kp[q] * kp[q];
            dots[2] += r[q] * kr[q];
            dots[3] += kp[q] * kr[q];
            dots[4] += kp[q] * k2p[q];
            dots[5] += k2p[q] * k2p[q];
            dots[6] += kr[q] * kr[q];
            dots[7] += kr[q] * k2p[q];
        }
        // publish edge pairs (relaxed; covered by the release tag via barrier)
        if (tid == 0) {
            sys_st64(LP + PW_L0, pack2(kp[0], kp[1]));
            sys_st64(LP + PW_L1, pack2(kr[0], kr[1]));
            sys_st64(LP + PW_L2, pack2(k2p[0], k2p[1]));
        }
        if (tid == CGBLK - 1) {
            sys_st64(LP + PW_R0, pack2(kp[E - 2], kp[E - 1]));
            sys_st64(LP + PW_R1, pack2(kr[E - 2], kr[E - 1]));
            sys_st64(LP + PW_R2, pack2(k2p[E - 2], k2p[E - 1]));
        }
        // block-reduce 8 dots
        #pragma unroll
        for (int off = 32; off > 0; off >>= 1)
            #pragma unroll
            for (int s = 0; s < 8; ++s) dots[s] += __shfl_down(dots[s], off, 64);
        {
            int lane = tid & 63, wid = tid >> 6;
            if (lane == 0)
                #pragma unroll
                for (int s = 0; s < 8; ++s) sred[wid][s] = dots[s];
        }
        __syncthreads();
        if (tid == 0) {
            float d0[8];
            #pragma unroll
            for (int s = 0; s < 8; ++s)
                d0[s] = sred[0][s] + sred[1][s] + sred[2][s] + sred[3][s];
            sys_st64(LP + PW_AB, pack2(d0[0], d0[1]));
            sys_st64(LP + PW_EF, pack2(d0[2], d0[3]));
            sys_st64(LP + PW_GH, pack2(d0[4], d0[5]));
            sys_st64(LP + PW_KL, pack2(d0[6], d0[7]));
            if (t == 0) sys_st64(LP + PW_RS0, pack2(s0b, 0.f));
            sys_st64_rel(LP + PW_TAG, mkword(G, 0.f));
        }
        // ---- single-tag all-to-all poll ----
        {
            int lane = tid & 63, wid = tid >> 6;
            if (wid == 0 && lane < bpb) {
                unsigned long long* LN = LINE(par, bbase + lane);
                poll_tag(LN + PW_TAG, G);
                unsigned long long w0 = sys_ld64(LN + PW_AB);
                unsigned long long w1 = sys_ld64(LN + PW_EF);
                unsigned long long w2 = sys_ld64(LN + PW_GH);
                unsigned long long w3 = sys_ld64(LN + PW_KL);
                unsigned long long e0 = sys_ld64(LN + PW_L0);
                unsigned long long e1 = sys_ld64(LN + PW_L1);
                unsigned long long e2 = sys_ld64(LN + PW_L2);
                unsigned long long e3 = sys_ld64(LN + PW_R0);
                unsigned long long e4 = sys_ld64(LN + PW_R1);
                unsigned long long e5 = sys_ld64(LN + PW_R2);
                float dt[9];
                dt[0] = lo2(w0); dt[1] = hi2(w0); dt[2] = lo2(w1); dt[3] = hi2(w1);
                dt[4] = lo2(w2); dt[5] = hi2(w2); dt[6] = lo2(w3); dt[7] = hi2(w3);
                dt[8] = (t == 0) ? lo2(sys_ld64(LN + PW_RS0)) : 0.f;
                eLb[lane][0] = lo2(e0); eLb[lane][1] = hi2(e0);
                eLb[lane][2] = lo2(e1); eLb[lane][3] = hi2(e1);
                eLb[lane][4] = lo2(e2); eLb[lane][5] = hi2(e2);
                eRb[lane][0] = lo2(e3); eRb[lane][1] = hi2(e3);
                eRb[lane][2] = lo2(e4); eRb[lane][3] = hi2(e4);
                eRb[lane][4] = lo2(e5); eRb[lane][5] = hi2(e5);
                #pragma unroll
                for (int off = 16; off > 0; off >>= 1)
                    #pragma unroll
                    for (int s = 0; s < 9; ++s) dt[s] += __shfl_down(dt[s], off, 32);
                if (lane == 0)
                    #pragma unroll
                    for (int s = 0; s < 9; ++s) sm[s] = dt[s];
            }
        }
        __syncthreads();
        // scalar recurrences (identical on every thread/block)
        float A = sm[0], D = sm[1], Ee = sm[2], F = sm[3];
        float Gg = sm[4], H = sm[5], Kk = sm[6], Ll = sm[7];
        if (t == 0) rs = sm[8];
        float alpha = rs / (A + 1e-30f);
        float rs1 = fmaxf(alpha * alpha * D - rs, 0.f);
        float betaI = rs1 / (rs + 1e-30f);
        float rKr1 = Ee - 2.f * alpha * F + alpha * alpha * Gg;
        float pKp1 = fmaxf(rKr1 + 2.f * betaI * (A - alpha * D) + betaI * betaI * A, 0.f);
        float alpha1 = rs1 / (pKp1 + 1e-30f);
        float KrKr1 = Kk - 2.f * alpha * Ll + alpha * alpha * H;
        float KpKp1 = fmaxf(KrKr1 + 2.f * betaI * (F - alpha * Gg) + betaI * betaI * D, 0.f);
        float rs2 = fmaxf(alpha1 * alpha1 * KpKp1 - rs1, 0.f);
        float betaN = rs2 / (rs1 + 1e-30f);
        // two CG iterations, locally
        #pragma unroll
        for (int q = 0; q < E; ++q) {
            vv[q] += alpha * p[q];
            float r1 = r[q] - alpha * kp[q];
            float kr1 = kr[q] - alpha * k2p[q];
            float kp1 = kr1 + betaI * kp[q];
            float p1 = r1 + betaI * p[q];
            vv[q] += alpha1 * p1;
            r[q] = r1 - alpha1 * kp1;
            p[q] = p1;
        }
        // mirror updates (same recurrences, neighbor's published edge values)
        if (tid == 0 && !first) {
            int li = (blk - 1) - bbase;
            float kpn0 = eRb[li][0], kpn1 = eRb[li][1];
            float krn0 = eRb[li][2], krn1 = eRb[li][3];
            float k2n0 = eRb[li][4], k2n1 = eRb[li][5];
            float r10 = r_nb0 - alpha * kpn0, r11 = r_nb1 - alpha * kpn1;
            float kr10 = krn0 - alpha * k2n0, kr11 = krn1 - alpha * k2n1;
            float kp10 = kr10 + betaI * kpn0, kp11 = kr11 + betaI * kpn1;
            float p10 = r10 + betaI * p_nb0, p11 = r11 + betaI * p_nb1;
            r_nb0 = r10 - alpha1 * kp10; r_nb1 = r11 - alpha1 * kp11;
            p_nb0 = p10; p_nb1 = p11;
        }
        if (tid == CGBLK - 1 && !last) {
            int li = (blk + 1) - bbase;
            float kpn0 = eLb[li][0], kpn1 = eLb[li][1];
            float krn0 = eLb[li][2], krn1 = eLb[li][3];
            float k2n0 = eLb[li][4], k2n1 = eLb[li][5];
            float r10 = r_nb0 - alpha * kpn0, r11 = r_nb1 - alpha * kpn1;
            float kr10 = krn0 - alpha * k2n0, kr11 = krn1 - alpha * k2n1;
            float kp10 = kr10 + betaI * kpn0, kp11 = kr11 + betaI * kpn1;
            float p10 = r10 + betaI * p_nb0, p11 = r11 + betaI * p_nb1;
            r_nb0 = r10 - alpha1 * kp10; r_nb1 = r11 - alpha1 * kp11;
            p_nb0 = p10; p_nb1 = p11;
        }
        rs = rs2; beta = betaN;
    }

    // ---- publish v0; v writeout (coalesced) ----
    const unsigned FG = (unsigned)(NROUND + 2);   // 12
    if (tid == 0) sys_st64(LINE(0, blk) + PW_V0, mkword(FG, vv[0]));
    float* vb = v_out + (size_t)b * K + (size_t)(blk - bbase) * CHUNK + (size_t)tid * E;
    #pragma unroll
    for (int q4 = 0; q4 < E / 4; ++q4)
        reinterpret_cast<float4*>(vb)[q4] =
            make_float4(vv[4 * q4], vv[4 * q4 + 1], vv[4 * q4 + 2], vv[4 * q4 + 3]);

    int jl[E + 1];
    {
        const int4* ip = reinterpret_cast<const int4*>(idx + k0);
        #pragma unroll
        for (int q4 = 0; q4 < E / 4; ++q4) {
            int4 t4 = ip[q4];
            jl[4 * q4] = t4.x; jl[4 * q4 + 1] = t4.y;
            jl[4 * q4 + 2] = t4.z; jl[4 * q4 + 3] = t4.w;
        }
        jl[E] = (k0 + E < K) ? idx[k0 + E] : n;
    }

    float* wb = w_out + (size_t)b * m;
    float* rb = r_out + (size_t)b * m;
    float phi_acc = 0.f;

    if (staged) {
        if (tid == CGBLK - 1)
            sVN = last ? 0.f : payload(poll_tag(LINE(0, blk + 1) + PW_V0, FG));
        #pragma unroll
        for (int q = 0; q < E; ++q) sX[PAD(jl[q] - lo)] = vv[q];
        __syncthreads();
        int tLo = jloB - lo;
        int wrHi = (jhiB < m) ? jhiB : m;
        int tHi = wrHi - lo;
        float vnext = sVN;
        for (int t = tLo + tid; t < tHi; t += CGBLK) {
            int i = lo + t;
            float s_cur = sX[PAD(t)];
            float s_next = (i + 1 == jhiB) ? vnext : sX[PAD(t + 1)];
            float w = sW[PAD(t)];
            float rv = s_next - s_cur;
            wb[i] = w;
            rb[i] = rv;
            phi_acc += w * w * rv * rv;
        }
    } else {
        // fallback (span > SPAN_MAX; ~1e-17 probability): serial walk on global
        sEa[tid] = vv[0];
        __syncthreads();
        float v_next = 0.f;
        if (tid < CGBLK - 1)      v_next = sEa[tid + 1];
        else if (!last)           v_next = payload(poll_tag(LINE(0, blk + 1) + PW_V0, FG));
        const bool first_thread = first && (tid == 0);
        const bool last_thread  = last && (tid == CGBLK - 1);
        int j_lo = first_thread ? 0 : jl[0];
        int j_hi = last_thread ? n : jl[E];
        int kptr = 0;
        int i = j_lo;
        float s_cur;
        if (kptr < E && i == jl[kptr]) { s_cur = vv[kptr]; ++kptr; }
        else s_cur = nn(xb[i]);
        while (i < j_hi) {
            int ip = i + 1;
            float s_next;
            if (ip == j_hi) s_next = v_next;
            else if (kptr < E && ip == jl[kptr]) { s_next = vv[kptr]; ++kptr; }
            else s_next = nn(xb[ip]);
            if (i < m) {
                float wv = sp_w(ub[i]);
                float rv = s_next - s_cur;
                wb[i] = wv;
                rb[i] = rv;
                phi_acc += wv * wv * rv * rv;
            }
            s_cur = s_next;
            i = ip;
        }
    }

    // phi: one tagged all-to-all; batch leader single writer
    float pblk = blockReduceSum(phi_acc);
    if (tid == 0) sys_st64(LINE(0, blk) + PW_PHI, mkword(FG, pblk));
    if (first) {
        int lane = tid & 63, wid = tid >> 6;
        if (wid == 0) {
            float pv = 0.f;
            if (lane < bpb)
                pv = payload(poll_tag(LINE(0, bbase + lane) + PW_PHI, FG));
            #pragma unroll
            for (int off = 16; off > 0; off >>= 1) pv += __shfl_down(pv, off, 32);
            if (lane == 0) phi[b] = pv;
        }
    }
}

extern "C" void kernel_launch(void* const* d_in, const int* in_sizes, int n_in,
                              void* d_out, int out_size, void* d_ws, size_t ws_size,
                              hipStream_t stream) {
    const float* u  = (const float*)d_in[0];  // [B, n-1]
    const float* x  = (const float*)d_in[1];  // [B, n]
    const int* idx  = (const int*)d_in[2];    // [K], sorted

    const int B = 16;
    const int n = in_sizes[1] / B;   // 262144
    const int m = n - 1;             // 262143
    const int K = in_sizes[2];       // 131072
    const int NK = B * K;            // 2097152
    const int GRID = NK / CHUNK;     // 512 blocks = 2 per CU

    float* out   = (float*)d_out;
    float* phi   = out;                         // [B]
    float* v_out = out + B;                     // [B,K]
    float* r_out = v_out + (size_t)B * K;       // [B,m]
    float* w_out = r_out + (size_t)B * m;       // [B,m]

    (void)m;
    char* ws = (char*)d_ws;
    unsigned long long* slot = (unsigned long long*)ws;
    size_t slot_words = (size_t)2 * GRID * SLOT_STRIDE;   // 1MB

    hipMemsetAsync(slot, 0, sizeof(unsigned long long) * slot_words, stream);

    k_cg_pers<<<GRID, CGBLK, 0, stream>>>(idx, u, x, v_out, w_out, r_out, phi,
                                          slot, n, K, B, GRID);
}

// Round 16
// 129.100 us; speedup vs baseline: 1.1692x; 1.1692x over previous
//
#include <hip/hip_runtime.h>
#include <math.h>

#define MAX_ITER 20
#define NROUND (MAX_ITER / 2)
#define EPS_W 1e-3f
#define CLAMP_MIN 1e-4f
#define CLAMP_MAX 1e4f

#define E 16
#define CGBLK 256
#define CHUNK (E * CGBLK)  // 4096 elems/block; bpb = K/CHUNK = 32
#define SPAN_MAX 8960
#define PAD(t) ((t) + ((t) >> 5))
#define SPAN_PAD (SPAN_MAX + SPAN_MAX / 32)

// Per-block 1KB slot line. EVERY word is self-tagged {gen|float} -> single
// fabric hop per round (r15's release-tag + dependent reads = 3 hops, 11.5us/rnd;
// r14's self-tagged words = 3.4us/rnd).
#define SLOT_STRIDE 128
#define PW_DOT 0    // 0..7: the 8 Gram dots
#define PW_RS0 8    // ||r0||^2 block partial (t==0 only)
#define PW_LE 9     // 9..14: kp[0],kp[1],kr[0],kr[1],k2p[0],k2p[1]; init(par1): dg0,cl1,r0,r1
#define PW_RE 15    // 15..20: kp[E-2],kp[E-1],kr[E-2],kr[E-1],k2p[E-2],k2p[E-1]; init: dgE1,clE1,rE2,rE1
#define PW_V0 21
#define PW_PHI 22

__device__ __forceinline__ float sp_w(float u) {
    float sp = fmaxf(u, 0.f) + log1pf(expf(-fabsf(u)));
    float w = sp + EPS_W;
    return fminf(fmaxf(w, CLAMP_MIN), CLAMP_MAX);
}
__device__ __forceinline__ float nn(float x) { return (x == x) ? x : 0.f; }

__device__ __forceinline__ unsigned long long sys_ld64(const unsigned long long* p) {
    return __hip_atomic_load(p, __ATOMIC_RELAXED, __HIP_MEMORY_SCOPE_SYSTEM);
}
__device__ __forceinline__ unsigned long long sys_ld64_acq(const unsigned long long* p) {
    return __hip_atomic_load(p, __ATOMIC_ACQUIRE, __HIP_MEMORY_SCOPE_SYSTEM);
}
__device__ __forceinline__ void sys_st64(unsigned long long* p, unsigned long long v) {
    __hip_atomic_store(p, v, __ATOMIC_RELAXED, __HIP_MEMORY_SCOPE_SYSTEM);
}
__device__ __forceinline__ unsigned long long poll_tag(const unsigned long long* p, unsigned gen) {
    unsigned long long v; int s = 0;
    for (;;) {
        v = sys_ld64(p);
        if ((unsigned)(v >> 32) >= gen) return v;
        if ((++s & 63) == 0) {
            v = sys_ld64_acq(p);
            if ((unsigned)(v >> 32) >= gen) return v;
        }
        __builtin_amdgcn_s_sleep(1);
    }
}
// combined 4-word poll (issues all loads each attempt -> one latency)
__device__ __forceinline__ void poll4(const unsigned long long* base, unsigned gen,
                                      unsigned long long out[4]) {
    int s = 0;
    for (;;) {
        bool ok = true;
        #pragma unroll
        for (int i = 0; i < 4; ++i) {
            out[i] = sys_ld64(base + i);
            ok &= ((unsigned)(out[i] >> 32) >= gen);
        }
        if (ok) return;
        if ((++s & 63) == 0) (void)sys_ld64_acq(base);
        __builtin_amdgcn_s_sleep(1);
    }
}
__device__ __forceinline__ unsigned long long mkword(unsigned gen, float f) {
    return ((unsigned long long)gen << 32) | (unsigned long long)__float_as_uint(f);
}
__device__ __forceinline__ float payload(unsigned long long v) { return __uint_as_float((unsigned)v); }

// valid on tid 0 only
__device__ __forceinline__ float blockReduceSum(float v) {
    #pragma unroll
    for (int off = 32; off > 0; off >>= 1) v += __shfl_down(v, off, 64);
    __shared__ float smem[4];
    int lane = threadIdx.x & 63, wid = threadIdx.x >> 6;
    if (lane == 0) smem[wid] = v;
    __syncthreads();
    float r = 0.f;
    if (threadIdx.x == 0) r = smem[0] + smem[1] + smem[2] + smem[3];
    return r;
}

// CA-CG(2): 2 CG iterations per one-hop communication round (10 rounds).
// Plain launch; co-residency by capacity: waves_per_eu(2,2) + <80KB LDS ->
// 2 blocks/CU, grid 512 = 2 x 256 CU (spin rounds proven r5-r15).
__global__ __attribute__((amdgpu_flat_work_group_size(256, 256),
                          amdgpu_waves_per_eu(2, 2)))
void k_cg_pers(const int* __restrict__ idx, const float* __restrict__ u_all,
               const float* __restrict__ x, float* __restrict__ v_out,
               float* __restrict__ w_out, float* __restrict__ r_out,
               float* __restrict__ phi,
               unsigned long long* __restrict__ slot,   // [2][nblk][SLOT_STRIDE]
               int n, int K, int B, int nblk) {
    const int blk = blockIdx.x, tid = threadIdx.x;
    const int bpb = K / CHUNK;                  // 32
    const int b = blk / bpb, bbase = b * bpb;
    const bool first = (blk == bbase), last = (blk == bbase + bpb - 1);
    const int k0 = (blk - bbase) * CHUNK + tid * E;
    const int m = n - 1;
    const float* ub = u_all + (size_t)b * m;
    const float* xb = x + (size_t)b * n;

    auto LINE = [&](int par, int blk_) -> unsigned long long* {
        return slot + ((size_t)par * nblk + blk_) * SLOT_STRIDE;
    };

    __shared__ float sX[SPAN_PAD], sW[SPAN_PAD];
    __shared__ float sEa[CGBLK], sEb[CGBLK], sEc[CGBLK], sEd[CGBLK];
    __shared__ float sred[4][8];
    __shared__ float sm[9];
    __shared__ float sm2[12];
    __shared__ int sInfo[4];
    __shared__ float sVN;

    // ---- span + coalesced staging ----
    if (tid == 0) {
        int kblk = (blk - bbase) * CHUNK;
        int jlo = first ? 0 : idx[kblk];
        int jhi = last ? n : idx[kblk + CHUNK];
        int lo_ = (jlo > 0) ? jlo - 1 : 0;
        sInfo[0] = lo_; sInfo[1] = jhi - lo_; sInfo[2] = jlo; sInfo[3] = jhi;
    }
    __syncthreads();
    const int lo = sInfo[0], len = sInfo[1], jloB = sInfo[2], jhiB = sInfo[3];
    const bool staged = (len <= SPAN_MAX);
    if (staged) {
        for (int t = tid; t < len; t += CGBLK) {
            int i = lo + t;
            sX[PAD(t)] = nn(xb[i]);
            sW[PAD(t)] = (i < m) ? sp_w(ub[i]) : 0.f;
        }
        __syncthreads();
    }
    auto LXn = [&](int i) -> float { return staged ? sX[PAD(i - lo)] : nn(xb[i]); };
    auto LW  = [&](int i) -> float { return staged ? sW[PAD(i - lo)] : sp_w(ub[i]); };

    // ---- init: dg, cl, r0 ----
    int jj[E + 2];
    {
        const int4* ip = reinterpret_cast<const int4*>(idx + k0);
        #pragma unroll
        for (int q4 = 0; q4 < E / 4; ++q4) {
            int4 t4 = ip[q4];
            jj[1 + 4 * q4] = t4.x; jj[2 + 4 * q4] = t4.y;
            jj[3 + 4 * q4] = t4.z; jj[4 + 4 * q4] = t4.w;
        }
        jj[0]     = (k0 > 0)     ? idx[k0 - 1] : -1000000;
        jj[E + 1] = (k0 + E < K) ? idx[k0 + E] : -1000000;
    }
    float vv[E], r[E], p[E], dgr[E], clr[E + 1];
    float s0 = 0.f;
    #pragma unroll
    for (int q = 0; q < E; ++q) {
        int j = jj[q + 1];
        bool la = (jj[q] == j - 1);
        bool ra = (jj[q + 2] == j + 1);
        float wl = 0.f, wr = 0.f;
        if (j >= 1)     { float w = LW(j - 1); wl = w * w; }
        if (j <= n - 2) { float w = LW(j);     wr = w * w; }
        float rhs = 0.f;
        if (j >= 1 && !la)     rhs += wl * LXn(j - 1);
        if (j <= n - 2 && !ra) rhs += wr * LXn(j + 1);
        vv[q] = 0.f; r[q] = rhs; p[q] = 0.f;
        dgr[q] = wl + wr;
        clr[q] = la ? wl : 0.f;
        s0 += rhs * rhs;
    }
    {
        float cl8 = 0.f;
        int j8 = jj[E + 1];
        if ((k0 + E) < K && jj[E] == j8 - 1) { float w = LW(j8 - 1); cl8 = w * w; }
        clr[E] = cl8;
    }

    // ---- init publish: statics + r0 edges (parity-1 line, tag 1, self-tagged) ----
    {
        unsigned long long* L1 = LINE(1, blk);
        if (tid == 0) {
            sys_st64(L1 + PW_LE + 0, mkword(1u, dgr[0]));
            sys_st64(L1 + PW_LE + 1, mkword(1u, clr[1]));
            sys_st64(L1 + PW_LE + 2, mkword(1u, r[0]));
            sys_st64(L1 + PW_LE + 3, mkword(1u, r[1]));
        }
        if (tid == CGBLK - 1) {
            sys_st64(L1 + PW_RE + 0, mkword(1u, dgr[E - 1]));
            sys_st64(L1 + PW_RE + 1, mkword(1u, clr[E - 1]));
            sys_st64(L1 + PW_RE + 2, mkword(1u, r[E - 2]));
            sys_st64(L1 + PW_RE + 3, mkword(1u, r[E - 1]));
        }
    }
    float s0b = blockReduceSum(s0);

    // ---- init poll: neighbor statics + r0 edges ----
    float dgnL = 0.f, clnL = 0.f, dgnR = 0.f, clnR = 0.f;
    float p_nb0 = 0.f, p_nb1 = 0.f, r_nb0 = 0.f, r_nb1 = 0.f;
    if (tid == 0 && !first) {
        unsigned long long w4[4];
        poll4(LINE(1, blk - 1) + PW_RE, 1u, w4);
        dgnL = payload(w4[0]); clnL = payload(w4[1]);
        r_nb0 = payload(w4[2]); r_nb1 = payload(w4[3]);
    }
    if (tid == CGBLK - 1 && !last) {
        unsigned long long w4[4];
        poll4(LINE(1, blk + 1) + PW_LE, 1u, w4);
        dgnR = payload(w4[0]); clnR = payload(w4[1]);
        r_nb0 = payload(w4[2]); r_nb1 = payload(w4[3]);
    }

    float rs = 0.f, beta = 0.f;

    for (int t = 0; t < NROUND; ++t) {
        const unsigned G = (unsigned)(t + 2);
        const int par = t & 1;
        unsigned long long* LP = LINE(par, blk);
        float kp[E], kr[E], k2p[E];

        // p = r + beta*p (+ mirrors)
        #pragma unroll
        for (int q = 0; q < E; ++q) p[q] = r[q] + beta * p[q];
        if (tid == 0 || tid == CGBLK - 1) {
            p_nb0 = r_nb0 + beta * p_nb0;
            p_nb1 = r_nb1 + beta * p_nb1;
        }
        sEa[tid] = p[0]; sEb[tid] = p[E - 1]; sEc[tid] = r[0]; sEd[tid] = r[E - 1];
        __syncthreads();
        float pL = (tid > 0) ? sEb[tid - 1] : (first ? 0.f : p_nb1);
        float pR = (tid < CGBLK - 1) ? sEa[tid + 1] : (last ? 0.f : p_nb0);
        float rL = (tid > 0) ? sEd[tid - 1] : (first ? 0.f : r_nb1);
        float rR = (tid < CGBLK - 1) ? sEc[tid + 1] : (last ? 0.f : r_nb0);
        #pragma unroll
        for (int q = 0; q < E; ++q) {
            float pm = (q == 0) ? pL : p[q - 1];
            float pp = (q == E - 1) ? pR : p[q + 1];
            kp[q] = dgr[q] * p[q] - clr[q] * pm - clr[q + 1] * pp;
        }
        // publish kp edges early (self-tagged)
        if (tid == 0) {
            sys_st64(LP + PW_LE + 0, mkword(G, kp[0]));
            sys_st64(LP + PW_LE + 1, mkword(G, kp[1]));
        }
        if (tid == CGBLK - 1) {
            sys_st64(LP + PW_RE + 0, mkword(G, kp[E - 2]));
            sys_st64(LP + PW_RE + 1, mkword(G, kp[E - 1]));
        }
        float kpE = 0.f;
        if (tid == 0 && !first)
            kpE = dgnL * p_nb1 - clnL * p_nb0 - clr[0] * p[0];
        if (tid == CGBLK - 1 && !last)
            kpE = dgnR * p_nb0 - clr[E] * p[E - 1] - clnR * p_nb1;
        __syncthreads();
        sEa[tid] = kp[0]; sEb[tid] = kp[E - 1];
        __syncthreads();
        float kpL = (tid > 0) ? sEb[tid - 1] : (first ? 0.f : kpE);
        float kpR = (tid < CGBLK - 1) ? sEa[tid + 1] : (last ? 0.f : kpE);
        float dots[8] = {0.f, 0.f, 0.f, 0.f, 0.f, 0.f, 0.f, 0.f};
        #pragma unroll
        for (int q = 0; q < E; ++q) {
            float km = (q == 0) ? kpL : kp[q - 1];
            float kpp = (q == E - 1) ? kpR : kp[q + 1];
            k2p[q] = dgr[q] * kp[q] - clr[q] * km - clr[q + 1] * kpp;
            float rm = (q == 0) ? rL : r[q - 1];
            float rp = (q == E - 1) ? rR : r[q + 1];
            kr[q] = dgr[q] * r[q] - clr[q] * rm - clr[q + 1] * rp;
            dots[0] += p[q] * kp[q];
            dots[1] += kp[q] * kp[q];
            dots[2] += r[q] * kr[q];
            dots[3] += kp[q] * kr[q];
            dots[4] += kp[q] * k2p[q];
            dots[5] += k2p[q] * k2p[q];
            dots[6] += kr[q] * kr[q];
            dots[7] += kr[q] * k2p[q];
        }
        // publish kr/k2p edges (self-tagged)
        if (tid == 0) {
            sys_st64(LP + PW_LE + 2, mkword(G, kr[0]));
            sys_st64(LP + PW_LE + 3, mkword(G, kr[1]));
            sys_st64(LP + PW_LE + 4, mkword(G, k2p[0]));
            sys_st64(LP + PW_LE + 5, mkword(G, k2p[1]));
        }
        if (tid == CGBLK - 1) {
            sys_st64(LP + PW_RE + 2, mkword(G, kr[E - 2]));
            sys_st64(LP + PW_RE + 3, mkword(G, kr[E - 1]));
            sys_st64(LP + PW_RE + 4, mkword(G, k2p[E - 2]));
            sys_st64(LP + PW_RE + 5, mkword(G, k2p[E - 1]));
        }
        // block-reduce 8 dots
        #pragma unroll
        for (int off = 32; off > 0; off >>= 1)
            #pragma unroll
            for (int s = 0; s < 8; ++s) dots[s] += __shfl_down(dots[s], off, 64);
        {
            int lane = tid & 63, wid = tid >> 6;
            if (lane == 0)
                #pragma unroll
                for (int s = 0; s < 8; ++s) sred[wid][s] = dots[s];
        }
        __syncthreads();
        if (tid == 0) {
            #pragma unroll
            for (int s = 0; s < 8; ++s) {
                float d0 = sred[0][s] + sred[1][s] + sred[2][s] + sred[3][s];
                sys_st64(LP + PW_DOT + s, mkword(G, d0));
            }
            if (t == 0) sys_st64(LP + PW_RS0, mkword(G, s0b));
        }
        // ---- one-hop combined poll: 256 threads x (dot word [+ edge word] [+ rs0]) ----
        {
            int pb = tid >> 3, pw = tid & 7;
            const unsigned long long* wA = LINE(par, bbase + pb) + PW_DOT + pw;
            int el = tid - 128;
            bool needB = false;
            const unsigned long long* wB = wA;
            if (el >= 0 && el < 6 && !first)      { needB = true; wB = LINE(par, blk - 1) + PW_RE + el; }
            else if (el >= 6 && el < 12 && !last) { needB = true; wB = LINE(par, blk + 1) + PW_LE + (el - 6); }
            bool needC = (t == 0) && (tid >= 192) && (tid < 192 + bpb);
            const unsigned long long* wC = needC ? (LINE(0, bbase + (tid - 192)) + PW_RS0) : wA;
            unsigned long long vA, vB = 0, vC = 0;
            int s = 0;
            for (;;) {
                vA = sys_ld64(wA);
                if (needB) vB = sys_ld64(wB);
                if (needC) vC = sys_ld64(wC);
                bool ok = ((unsigned)(vA >> 32) >= G)
                       && (!needB || (unsigned)(vB >> 32) >= G)
                       && (!needC || (unsigned)(vC >> 32) >= 2u);
                if (ok) break;
                if ((++s & 63) == 0) (void)sys_ld64_acq(wA);
                __builtin_amdgcn_s_sleep(1);
            }
            float dv = payload(vA);
            dv += __shfl_xor(dv, 8, 64);
            dv += __shfl_xor(dv, 16, 64);
            dv += __shfl_xor(dv, 32, 64);
            int lane = tid & 63, wid = tid >> 6;
            if (lane < 8) sred[wid][lane] = dv;
            if (needB) sm2[el] = payload(vB);
            if (needC) {
                float rv = payload(vC);
                #pragma unroll
                for (int off = 16; off > 0; off >>= 1) rv += __shfl_down(rv, off, 32);
                if (tid == 192) sm[8] = rv;
            }
        }
        __syncthreads();
        if (tid < 8) sm[tid] = sred[0][tid] + sred[1][tid] + sred[2][tid] + sred[3][tid];
        __syncthreads();
        // scalar recurrences (identical on every thread/block)
        float A = sm[0], D = sm[1], Ee = sm[2], F = sm[3];
        float Gg = sm[4], H = sm[5], Kk = sm[6], Ll = sm[7];
        if (t == 0) rs = sm[8];
        float alpha = rs / (A + 1e-30f);
        float rs1 = fmaxf(alpha * alpha * D - rs, 0.f);
        float betaI = rs1 / (rs + 1e-30f);
        float rKr1 = Ee - 2.f * alpha * F + alpha * alpha * Gg;
        float pKp1 = fmaxf(rKr1 + 2.f * betaI * (A - alpha * D) + betaI * betaI * A, 0.f);
        float alpha1 = rs1 / (pKp1 + 1e-30f);
        float KrKr1 = Kk - 2.f * alpha * Ll + alpha * alpha * H;
        float KpKp1 = fmaxf(KrKr1 + 2.f * betaI * (F - alpha * Gg) + betaI * betaI * D, 0.f);
        float rs2 = fmaxf(alpha1 * alpha1 * KpKp1 - rs1, 0.f);
        float betaN = rs2 / (rs1 + 1e-30f);
        #pragma unroll
        for (int q = 0; q < E; ++q) {
            vv[q] += alpha * p[q];
            float r1 = r[q] - alpha * kp[q];
            float kr1 = kr[q] - alpha * k2p[q];
            float kp1 = kr1 + betaI * kp[q];
            float p1 = r1 + betaI * p[q];
            vv[q] += alpha1 * p1;
            r[q] = r1 - alpha1 * kp1;
            p[q] = p1;
        }
        if (tid == 0 && !first) {
            float kpn0 = sm2[0], kpn1 = sm2[1];
            float krn0 = sm2[2], krn1 = sm2[3];
            float k2n0 = sm2[4], k2n1 = sm2[5];
            float r10 = r_nb0 - alpha * kpn0, r11 = r_nb1 - alpha * kpn1;
            float kr10 = krn0 - alpha * k2n0, kr11 = krn1 - alpha * k2n1;
            float kp10 = kr10 + betaI * kpn0, kp11 = kr11 + betaI * kpn1;
            float p10 = r10 + betaI * p_nb0, p11 = r11 + betaI * p_nb1;
            r_nb0 = r10 - alpha1 * kp10; r_nb1 = r11 - alpha1 * kp11;
            p_nb0 = p10; p_nb1 = p11;
        }
        if (tid == CGBLK - 1 && !last) {
            float kpn0 = sm2[6], kpn1 = sm2[7];
            float krn0 = sm2[8], krn1 = sm2[9];
            float k2n0 = sm2[10], k2n1 = sm2[11];
            float r10 = r_nb0 - alpha * kpn0, r11 = r_nb1 - alpha * kpn1;
            float kr10 = krn0 - alpha * k2n0, kr11 = krn1 - alpha * k2n1;
            float kp10 = kr10 + betaI * kpn0, kp11 = kr11 + betaI * kpn1;
            float p10 = r10 + betaI * p_nb0, p11 = r11 + betaI * p_nb1;
            r_nb0 = r10 - alpha1 * kp10; r_nb1 = r11 - alpha1 * kp11;
            p_nb0 = p10; p_nb1 = p11;
        }
        rs = rs2; beta = betaN;
    }

    // ---- publish v0; v writeout (coalesced) ----
    const unsigned FG = (unsigned)(NROUND + 2);   // 12
    if (tid == 0) sys_st64(LINE(0, blk) + PW_V0, mkword(FG, vv[0]));
    float* vb = v_out + (size_t)b * K + (size_t)(blk - bbase) * CHUNK + (size_t)tid * E;
    #pragma unroll
    for (int q4 = 0; q4 < E / 4; ++q4)
        reinterpret_cast<float4*>(vb)[q4] =
            make_float4(vv[4 * q4], vv[4 * q4 + 1], vv[4 * q4 + 2], vv[4 * q4 + 3]);

    int jl[E + 1];
    {
        const int4* ip = reinterpret_cast<const int4*>(idx + k0);
        #pragma unroll
        for (int q4 = 0; q4 < E / 4; ++q4) {
            int4 t4 = ip[q4];
            jl[4 * q4] = t4.x; jl[4 * q4 + 1] = t4.y;
            jl[4 * q4 + 2] = t4.z; jl[4 * q4 + 3] = t4.w;
        }
        jl[E] = (k0 + E < K) ? idx[k0 + E] : n;
    }

    float* wb = w_out + (size_t)b * m;
    float* rb = r_out + (size_t)b * m;
    float phi_acc = 0.f;

    if (staged) {
        if (tid == CGBLK - 1)
            sVN = last ? 0.f : payload(poll_tag(LINE(0, blk + 1) + PW_V0, FG));
        #pragma unroll
        for (int q = 0; q < E; ++q) sX[PAD(jl[q] - lo)] = vv[q];
        __syncthreads();
        int tLo = jloB - lo;
        int wrHi = (jhiB < m) ? jhiB : m;
        int tHi = wrHi - lo;
        float vnext = sVN;
        for (int t = tLo + tid; t < tHi; t += CGBLK) {
            int i = lo + t;
            float s_cur = sX[PAD(t)];
            float s_next = (i + 1 == jhiB) ? vnext : sX[PAD(t + 1)];
            float w = sW[PAD(t)];
            float rv = s_next - s_cur;
            wb[i] = w;
            rb[i] = rv;
            phi_acc += w * w * rv * rv;
        }
    } else {
        // fallback (span > SPAN_MAX; ~improbable): serial walk on global
        sEa[tid] = vv[0];
        __syncthreads();
        float v_next = 0.f;
        if (tid < CGBLK - 1)      v_next = sEa[tid + 1];
        else if (!last)           v_next = payload(poll_tag(LINE(0, blk + 1) + PW_V0, FG));
        const bool first_thread = first && (tid == 0);
        const bool last_thread  = last && (tid == CGBLK - 1);
        int j_lo = first_thread ? 0 : jl[0];
        int j_hi = last_thread ? n : jl[E];
        int kptr = 0;
        int i = j_lo;
        float s_cur;
        if (kptr < E && i == jl[kptr]) { s_cur = vv[kptr]; ++kptr; }
        else s_cur = nn(xb[i]);
        while (i < j_hi) {
            int ip = i + 1;
            float s_next;
            if (ip == j_hi) s_next = v_next;
            else if (kptr < E && ip == jl[kptr]) { s_next = vv[kptr]; ++kptr; }
            else s_next = nn(xb[ip]);
            if (i < m) {
                float wv = sp_w(ub[i]);
                float rv = s_next - s_cur;
                wb[i] = wv;
                rb[i] = rv;
                phi_acc += wv * wv * rv * rv;
            }
            s_cur = s_next;
            i = ip;
        }
    }

    // phi: one tagged all-to-all; batch leader single writer
    float pblk = blockReduceSum(phi_acc);
    if (tid == 0) sys_st64(LINE(0, blk) + PW_PHI, mkword(FG, pblk));
    if (first) {
        int lane = tid & 63, wid = tid >> 6;
        if (wid == 0) {
            float pv = 0.f;
            if (lane < bpb)
                pv = payload(poll_tag(LINE(0, bbase + lane) + PW_PHI, FG));
            #pragma unroll
            for (int off = 16; off > 0; off >>= 1) pv += __shfl_down(pv, off, 32);
            if (lane == 0) phi[b] = pv;
        }
    }
}

extern "C" void kernel_launch(void* const* d_in, const int* in_sizes, int n_in,
                              void* d_out, int out_size, void* d_ws, size_t ws_size,
                              hipStream_t stream) {
    const float* u  = (const float*)d_in[0];  // [B, n-1]
    const float* x  = (const float*)d_in[1];  // [B, n]
    const int* idx  = (const int*)d_in[2];    // [K], sorted

    const int B = 16;
    const int n = in_sizes[1] / B;   // 262144
    const int m = n - 1;             // 262143
    const int K = in_sizes[2];       // 131072
    const int NK = B * K;            // 2097152
    const int GRID = NK / CHUNK;     // 512 blocks = 2 per CU

    float* out   = (float*)d_out;
    float* phi   = out;                         // [B]
    float* v_out = out + B;                     // [B,K]
    float* r_out = v_out + (size_t)B * K;       // [B,m]
    float* w_out = r_out + (size_t)B * m;       // [B,m]

    (void)m;
    char* ws = (char*)d_ws;
    unsigned long long* slot = (unsigned long long*)ws;
    size_t slot_words = (size_t)2 * GRID * SLOT_STRIDE;   // 1MB

    hipMemsetAsync(slot, 0, sizeof(unsigned long long) * slot_words, stream);

    k_cg_pers<<<GRID, CGBLK, 0, stream>>>(idx, u, x, v_out, w_out, r_out, phi,
                                          slot, n, K, B, GRID);
}

// Round 17
// 122.875 us; speedup vs baseline: 1.2285x; 1.0507x over previous
//
#include <hip/hip_runtime.h>
#include <math.h>

#define MAX_ITER 20
#define NROUND (MAX_ITER / 2)
#define EPS_W 1e-3f
#define CLAMP_MIN 1e-4f
#define CLAMP_MAX 1e4f

#define E 16
#define CGBLK 256
#define CHUNK (E * CGBLK)  // 4096 elems/block; bpb = K/CHUNK = 32
#define SPAN_MAX 8960
#define PAD(t) ((t) + ((t) >> 5))
#define SPAN_PAD (SPAN_MAX + SPAN_MAX / 32)

// Per-block 1KB slot line; every word self-tagged {gen|float} (one-hop reads).
#define SLOT_STRIDE 128
#define PW_DOT 0    // 0..7: block-partial Gram dots
#define PW_RS0 8    // ||r0||^2 block partial (t==0 only)
#define PW_LE 9     // 9..14: kp0,kp1,kr0,kr1,k2p0,k2p1; init(par1): dg0,cl1,r0,r1
#define PW_RE 15    // 15..20: right-edge equivalents
#define PW_V0 21
#define PW_PHI 22
#define PW_SUM 24   // 24..32: leader-published batch sums (8 dots [+ rs0 at 32])

__device__ __forceinline__ float sp_w(float u) {
    float sp = fmaxf(u, 0.f) + log1pf(expf(-fabsf(u)));
    float w = sp + EPS_W;
    return fminf(fmaxf(w, CLAMP_MIN), CLAMP_MAX);
}
__device__ __forceinline__ float nn(float x) { return (x == x) ? x : 0.f; }

__device__ __forceinline__ unsigned long long sys_ld64(const unsigned long long* p) {
    return __hip_atomic_load(p, __ATOMIC_RELAXED, __HIP_MEMORY_SCOPE_SYSTEM);
}
__device__ __forceinline__ unsigned long long sys_ld64_acq(const unsigned long long* p) {
    return __hip_atomic_load(p, __ATOMIC_ACQUIRE, __HIP_MEMORY_SCOPE_SYSTEM);
}
__device__ __forceinline__ void sys_st64(unsigned long long* p, unsigned long long v) {
    __hip_atomic_store(p, v, __ATOMIC_RELAXED, __HIP_MEMORY_SCOPE_SYSTEM);
}
__device__ __forceinline__ unsigned long long poll_tag(const unsigned long long* p, unsigned gen) {
    unsigned long long v; int s = 0;
    for (;;) {
        v = sys_ld64(p);
        if ((unsigned)(v >> 32) >= gen) return v;
        if ((++s & 63) == 0) {
            v = sys_ld64_acq(p);
            if ((unsigned)(v >> 32) >= gen) return v;
        }
        __builtin_amdgcn_s_sleep(1);
    }
}
// combined 4-word poll (all loads issued each retry -> one latency)
__device__ __forceinline__ void poll4(const unsigned long long* base, unsigned gen,
                                      unsigned long long out[4]) {
    int s = 0;
    for (;;) {
        bool ok = true;
        #pragma unroll
        for (int i = 0; i < 4; ++i) {
            out[i] = sys_ld64(base + i);
            ok &= ((unsigned)(out[i] >> 32) >= gen);
        }
        if (ok) return;
        if ((++s & 63) == 0) (void)sys_ld64_acq(base);
        __builtin_amdgcn_s_sleep(1);
    }
}
__device__ __forceinline__ unsigned long long mkword(unsigned gen, float f) {
    return ((unsigned long long)gen << 32) | (unsigned long long)__float_as_uint(f);
}
__device__ __forceinline__ float payload(unsigned long long v) { return __uint_as_float((unsigned)v); }

// valid on tid 0 only
__device__ __forceinline__ float blockReduceSum(float v) {
    #pragma unroll
    for (int off = 32; off > 0; off >>= 1) v += __shfl_down(v, off, 64);
    __shared__ float smem[4];
    int lane = threadIdx.x & 63, wid = threadIdx.x >> 6;
    if (lane == 0) smem[wid] = v;
    __syncthreads();
    float r = 0.f;
    if (threadIdx.x == 0) r = smem[0] + smem[1] + smem[2] + smem[3];
    return r;
}

// CA-CG(2), leader-gather reduction (2 light hops/round, 10 rounds).
// Plain launch; co-residency by capacity: waves_per_eu(2,2) + <80KB LDS ->
// 2 blocks/CU, grid 512 = 2 x 256 CU (spin rounds proven r5-r16).
__global__ __attribute__((amdgpu_flat_work_group_size(256, 256),
                          amdgpu_waves_per_eu(2, 2)))
void k_cg_pers(const int* __restrict__ idx, const float* __restrict__ u_all,
               const float* __restrict__ x, float* __restrict__ v_out,
               float* __restrict__ w_out, float* __restrict__ r_out,
               float* __restrict__ phi,
               unsigned long long* __restrict__ slot,   // [2][nblk][SLOT_STRIDE]
               int n, int K, int B, int nblk) {
    const int blk = blockIdx.x, tid = threadIdx.x;
    const int bpb = K / CHUNK;                  // 32
    const int b = blk / bpb, bbase = b * bpb;
    const bool first = (blk == bbase), last = (blk == bbase + bpb - 1);
    const int k0 = (blk - bbase) * CHUNK + tid * E;
    const int m = n - 1;
    const float* ub = u_all + (size_t)b * m;
    const float* xb = x + (size_t)b * n;

    auto LINE = [&](int par, int blk_) -> unsigned long long* {
        return slot + ((size_t)par * nblk + blk_) * SLOT_STRIDE;
    };

    __shared__ float sX[SPAN_PAD], sW[SPAN_PAD];
    __shared__ float sEa[CGBLK], sEb[CGBLK], sEc[CGBLK], sEd[CGBLK];
    __shared__ float sred[4][8];
    __shared__ float sm[9];
    __shared__ float sm2[12];
    __shared__ int sInfo[4];
    __shared__ float sVN;

    // ---- span + coalesced staging ----
    if (tid == 0) {
        int kblk = (blk - bbase) * CHUNK;
        int jlo = first ? 0 : idx[kblk];
        int jhi = last ? n : idx[kblk + CHUNK];
        int lo_ = (jlo > 0) ? jlo - 1 : 0;
        sInfo[0] = lo_; sInfo[1] = jhi - lo_; sInfo[2] = jlo; sInfo[3] = jhi;
    }
    __syncthreads();
    const int lo = sInfo[0], len = sInfo[1], jloB = sInfo[2], jhiB = sInfo[3];
    const bool staged = (len <= SPAN_MAX);
    if (staged) {
        for (int t = tid; t < len; t += CGBLK) {
            int i = lo + t;
            sX[PAD(t)] = nn(xb[i]);
            sW[PAD(t)] = (i < m) ? sp_w(ub[i]) : 0.f;
        }
        __syncthreads();
    }
    auto LXn = [&](int i) -> float { return staged ? sX[PAD(i - lo)] : nn(xb[i]); };
    auto LW  = [&](int i) -> float { return staged ? sW[PAD(i - lo)] : sp_w(ub[i]); };

    // ---- init: dg, cl, r0 ----
    int jj[E + 2];
    {
        const int4* ip = reinterpret_cast<const int4*>(idx + k0);
        #pragma unroll
        for (int q4 = 0; q4 < E / 4; ++q4) {
            int4 t4 = ip[q4];
            jj[1 + 4 * q4] = t4.x; jj[2 + 4 * q4] = t4.y;
            jj[3 + 4 * q4] = t4.z; jj[4 + 4 * q4] = t4.w;
        }
        jj[0]     = (k0 > 0)     ? idx[k0 - 1] : -1000000;
        jj[E + 1] = (k0 + E < K) ? idx[k0 + E] : -1000000;
    }
    float vv[E], r[E], p[E], dgr[E], clr[E + 1];
    float s0 = 0.f;
    #pragma unroll
    for (int q = 0; q < E; ++q) {
        int j = jj[q + 1];
        bool la = (jj[q] == j - 1);
        bool ra = (jj[q + 2] == j + 1);
        float wl = 0.f, wr = 0.f;
        if (j >= 1)     { float w = LW(j - 1); wl = w * w; }
        if (j <= n - 2) { float w = LW(j);     wr = w * w; }
        float rhs = 0.f;
        if (j >= 1 && !la)     rhs += wl * LXn(j - 1);
        if (j <= n - 2 && !ra) rhs += wr * LXn(j + 1);
        vv[q] = 0.f; r[q] = rhs; p[q] = 0.f;
        dgr[q] = wl + wr;
        clr[q] = la ? wl : 0.f;
        s0 += rhs * rhs;
    }
    {
        float cl8 = 0.f;
        int j8 = jj[E + 1];
        if ((k0 + E) < K && jj[E] == j8 - 1) { float w = LW(j8 - 1); cl8 = w * w; }
        clr[E] = cl8;
    }

    // ---- init publish: statics + r0 edges (parity-1 line, tag 1, self-tagged) ----
    {
        unsigned long long* L1 = LINE(1, blk);
        if (tid == 0) {
            sys_st64(L1 + PW_LE + 0, mkword(1u, dgr[0]));
            sys_st64(L1 + PW_LE + 1, mkword(1u, clr[1]));
            sys_st64(L1 + PW_LE + 2, mkword(1u, r[0]));
            sys_st64(L1 + PW_LE + 3, mkword(1u, r[1]));
        }
        if (tid == CGBLK - 1) {
            sys_st64(L1 + PW_RE + 0, mkword(1u, dgr[E - 1]));
            sys_st64(L1 + PW_RE + 1, mkword(1u, clr[E - 1]));
            sys_st64(L1 + PW_RE + 2, mkword(1u, r[E - 2]));
            sys_st64(L1 + PW_RE + 3, mkword(1u, r[E - 1]));
        }
    }
    float s0b = blockReduceSum(s0);

    // ---- init poll: neighbor statics + r0 edges ----
    float dgnL = 0.f, clnL = 0.f, dgnR = 0.f, clnR = 0.f;
    float p_nb0 = 0.f, p_nb1 = 0.f, r_nb0 = 0.f, r_nb1 = 0.f;
    if (tid == 0 && !first) {
        unsigned long long w4[4];
        poll4(LINE(1, blk - 1) + PW_RE, 1u, w4);
        dgnL = payload(w4[0]); clnL = payload(w4[1]);
        r_nb0 = payload(w4[2]); r_nb1 = payload(w4[3]);
    }
    if (tid == CGBLK - 1 && !last) {
        unsigned long long w4[4];
        poll4(LINE(1, blk + 1) + PW_LE, 1u, w4);
        dgnR = payload(w4[0]); clnR = payload(w4[1]);
        r_nb0 = payload(w4[2]); r_nb1 = payload(w4[3]);
    }

    float rs = 0.f, beta = 0.f;

    for (int t = 0; t < NROUND; ++t) {
        const unsigned G = (unsigned)(t + 2);
        const int par = t & 1;
        unsigned long long* LP = LINE(par, blk);
        float kp[E], kr[E], k2p[E];

        // p = r + beta*p (+ mirrors)
        #pragma unroll
        for (int q = 0; q < E; ++q) p[q] = r[q] + beta * p[q];
        if (tid == 0 || tid == CGBLK - 1) {
            p_nb0 = r_nb0 + beta * p_nb0;
            p_nb1 = r_nb1 + beta * p_nb1;
        }
        sEa[tid] = p[0]; sEb[tid] = p[E - 1]; sEc[tid] = r[0]; sEd[tid] = r[E - 1];
        __syncthreads();
        float pL = (tid > 0) ? sEb[tid - 1] : (first ? 0.f : p_nb1);
        float pR = (tid < CGBLK - 1) ? sEa[tid + 1] : (last ? 0.f : p_nb0);
        float rL = (tid > 0) ? sEd[tid - 1] : (first ? 0.f : r_nb1);
        float rR = (tid < CGBLK - 1) ? sEc[tid + 1] : (last ? 0.f : r_nb0);
        #pragma unroll
        for (int q = 0; q < E; ++q) {
            float pm = (q == 0) ? pL : p[q - 1];
            float pp = (q == E - 1) ? pR : p[q + 1];
            kp[q] = dgr[q] * p[q] - clr[q] * pm - clr[q + 1] * pp;
        }
        if (tid == 0) {
            sys_st64(LP + PW_LE + 0, mkword(G, kp[0]));
            sys_st64(LP + PW_LE + 1, mkword(G, kp[1]));
        }
        if (tid == CGBLK - 1) {
            sys_st64(LP + PW_RE + 0, mkword(G, kp[E - 2]));
            sys_st64(LP + PW_RE + 1, mkword(G, kp[E - 1]));
        }
        float kpE = 0.f;
        if (tid == 0 && !first)
            kpE = dgnL * p_nb1 - clnL * p_nb0 - clr[0] * p[0];
        if (tid == CGBLK - 1 && !last)
            kpE = dgnR * p_nb0 - clr[E] * p[E - 1] - clnR * p_nb1;
        __syncthreads();
        sEa[tid] = kp[0]; sEb[tid] = kp[E - 1];
        __syncthreads();
        float kpL = (tid > 0) ? sEb[tid - 1] : (first ? 0.f : kpE);
        float kpR = (tid < CGBLK - 1) ? sEa[tid + 1] : (last ? 0.f : kpE);
        float dots[8] = {0.f, 0.f, 0.f, 0.f, 0.f, 0.f, 0.f, 0.f};
        #pragma unroll
        for (int q = 0; q < E; ++q) {
            float km = (q == 0) ? kpL : kp[q - 1];
            float kpp = (q == E - 1) ? kpR : kp[q + 1];
            k2p[q] = dgr[q] * kp[q] - clr[q] * km - clr[q + 1] * kpp;
            float rm = (q == 0) ? rL : r[q - 1];
            float rp = (q == E - 1) ? rR : r[q + 1];
            kr[q] = dgr[q] * r[q] - clr[q] * rm - clr[q + 1] * rp;
            dots[0] += p[q] * kp[q];
            dots[1] += kp[q] * kp[q];
            dots[2] += r[q] * kr[q];
            dots[3] += kp[q] * kr[q];
            dots[4] += kp[q] * k2p[q];
            dots[5] += k2p[q] * k2p[q];
            dots[6] += kr[q] * kr[q];
            dots[7] += kr[q] * k2p[q];
        }
        if (tid == 0) {
            sys_st64(LP + PW_LE + 2, mkword(G, kr[0]));
            sys_st64(LP + PW_LE + 3, mkword(G, kr[1]));
            sys_st64(LP + PW_LE + 4, mkword(G, k2p[0]));
            sys_st64(LP + PW_LE + 5, mkword(G, k2p[1]));
        }
        if (tid == CGBLK - 1) {
            sys_st64(LP + PW_RE + 2, mkword(G, kr[E - 2]));
            sys_st64(LP + PW_RE + 3, mkword(G, kr[E - 1]));
            sys_st64(LP + PW_RE + 4, mkword(G, k2p[E - 2]));
            sys_st64(LP + PW_RE + 5, mkword(G, k2p[E - 1]));
        }
        // block-reduce 8 dots -> tid0 publishes block partials
        #pragma unroll
        for (int off = 32; off > 0; off >>= 1)
            #pragma unroll
            for (int s = 0; s < 8; ++s) dots[s] += __shfl_down(dots[s], off, 64);
        {
            int lane = tid & 63, wid = tid >> 6;
            if (lane == 0)
                #pragma unroll
                for (int s = 0; s < 8; ++s) sred[wid][s] = dots[s];
        }
        __syncthreads();
        if (tid == 0) {
            #pragma unroll
            for (int s = 0; s < 8; ++s) {
                float d0 = sred[0][s] + sred[1][s] + sred[2][s] + sred[3][s];
                sys_st64(LP + PW_DOT + s, mkword(G, d0));
            }
            if (t == 0) sys_st64(LP + PW_RS0, mkword(G, s0b));
        }
        // ---- hop1: leader gathers 32x8 partials; hop2: others read 8 sums ----
        {
            int lane = tid & 63, wid = tid >> 6;
            if (first) {
                if (wid == 0) {
                    int pb = lane >> 1, wbase = (lane & 1) * 4;
                    unsigned long long w4[4];
                    poll4(LINE(par, bbase + pb) + PW_DOT + wbase, G, w4);
                    float d0 = payload(w4[0]), d1 = payload(w4[1]);
                    float d2 = payload(w4[2]), d3 = payload(w4[3]);
                    #pragma unroll
                    for (int off = 2; off <= 32; off <<= 1) {
                        d0 += __shfl_xor(d0, off, 64);
                        d1 += __shfl_xor(d1, off, 64);
                        d2 += __shfl_xor(d2, off, 64);
                        d3 += __shfl_xor(d3, off, 64);
                    }
                    if (lane < 2) {
                        unsigned long long* sp = LINE(par, blk) + PW_SUM + wbase;
                        sys_st64(sp + 0, mkword(G, d0));
                        sys_st64(sp + 1, mkword(G, d1));
                        sys_st64(sp + 2, mkword(G, d2));
                        sys_st64(sp + 3, mkword(G, d3));
                        sm[wbase + 0] = d0; sm[wbase + 1] = d1;
                        sm[wbase + 2] = d2; sm[wbase + 3] = d3;
                    }
                } else if (wid == 2 && t == 0 && lane < bpb) {
                    float rv = payload(poll_tag(LINE(0, bbase + lane) + PW_RS0, 2u));
                    #pragma unroll
                    for (int off = 16; off > 0; off >>= 1) rv += __shfl_down(rv, off, 32);
                    if (lane == 0) {
                        sys_st64(LINE(0, blk) + PW_SUM + 8, mkword(2u, rv));
                        sm[8] = rv;
                    }
                }
            } else {
                int lim = (t == 0) ? 9 : 8;
                if (wid == 0 && lane < lim) {
                    const unsigned long long* wp = (lane < 8)
                        ? (LINE(par, bbase) + PW_SUM + lane)
                        : (LINE(0, bbase) + PW_SUM + 8);
                    unsigned tg = (lane < 8) ? G : 2u;
                    sm[lane] = payload(poll_tag(wp, tg));
                }
            }
            // neighbor edges: wave 1, lanes 0..11 (all blocks)
            if (wid == 1 && lane < 12) {
                const unsigned long long* wB = nullptr;
                if (lane < 6 && !first)       wB = LINE(par, blk - 1) + PW_RE + lane;
                else if (lane >= 6 && !last)  wB = LINE(par, blk + 1) + PW_LE + (lane - 6);
                if (wB) sm2[lane] = payload(poll_tag(wB, G));
            }
        }
        __syncthreads();
        // scalar recurrences (identical on every thread/block)
        float A = sm[0], D = sm[1], Ee = sm[2], F = sm[3];
        float Gg = sm[4], H = sm[5], Kk = sm[6], Ll = sm[7];
        if (t == 0) rs = sm[8];
        float alpha = rs / (A + 1e-30f);
        float rs1 = fmaxf(alpha * alpha * D - rs, 0.f);
        float betaI = rs1 / (rs + 1e-30f);
        float rKr1 = Ee - 2.f * alpha * F + alpha * alpha * Gg;
        float pKp1 = fmaxf(rKr1 + 2.f * betaI * (A - alpha * D) + betaI * betaI * A, 0.f);
        float alpha1 = rs1 / (pKp1 + 1e-30f);
        float KrKr1 = Kk - 2.f * alpha * Ll + alpha * alpha * H;
        float KpKp1 = fmaxf(KrKr1 + 2.f * betaI * (F - alpha * Gg) + betaI * betaI * D, 0.f);
        float rs2 = fmaxf(alpha1 * alpha1 * KpKp1 - rs1, 0.f);
        float betaN = rs2 / (rs1 + 1e-30f);
        #pragma unroll
        for (int q = 0; q < E; ++q) {
            vv[q] += alpha * p[q];
            float r1 = r[q] - alpha * kp[q];
            float kr1 = kr[q] - alpha * k2p[q];
            float kp1 = kr1 + betaI * kp[q];
            float p1 = r1 + betaI * p[q];
            vv[q] += alpha1 * p1;
            r[q] = r1 - alpha1 * kp1;
            p[q] = p1;
        }
        if (tid == 0 && !first) {
            float kpn0 = sm2[0], kpn1 = sm2[1];
            float krn0 = sm2[2], krn1 = sm2[3];
            float k2n0 = sm2[4], k2n1 = sm2[5];
            float r10 = r_nb0 - alpha * kpn0, r11 = r_nb1 - alpha * kpn1;
            float kr10 = krn0 - alpha * k2n0, kr11 = krn1 - alpha * k2n1;
            float kp10 = kr10 + betaI * kpn0, kp11 = kr11 + betaI * kpn1;
            float p10 = r10 + betaI * p_nb0, p11 = r11 + betaI * p_nb1;
            r_nb0 = r10 - alpha1 * kp10; r_nb1 = r11 - alpha1 * kp11;
            p_nb0 = p10; p_nb1 = p11;
        }
        if (tid == CGBLK - 1 && !last) {
            float kpn0 = sm2[6], kpn1 = sm2[7];
            float krn0 = sm2[8], krn1 = sm2[9];
            float k2n0 = sm2[10], k2n1 = sm2[11];
            float r10 = r_nb0 - alpha * kpn0, r11 = r_nb1 - alpha * kpn1;
            float kr10 = krn0 - alpha * k2n0, kr11 = krn1 - alpha * k2n1;
            float kp10 = kr10 + betaI * kpn0, kp11 = kr11 + betaI * kpn1;
            float p10 = r10 + betaI * p_nb0, p11 = r11 + betaI * p_nb1;
            r_nb0 = r10 - alpha1 * kp10; r_nb1 = r11 - alpha1 * kp11;
            p_nb0 = p10; p_nb1 = p11;
        }
        rs = rs2; beta = betaN;
    }

    // ---- publish v0; v writeout (coalesced) ----
    const unsigned FG = (unsigned)(NROUND + 2);   // 12
    if (tid == 0) sys_st64(LINE(0, blk) + PW_V0, mkword(FG, vv[0]));
    float* vb = v_out + (size_t)b * K + (size_t)(blk - bbase) * CHUNK + (size_t)tid * E;
    #pragma unroll
    for (int q4 = 0; q4 < E / 4; ++q4)
        reinterpret_cast<float4*>(vb)[q4] =
            make_float4(vv[4 * q4], vv[4 * q4 + 1], vv[4 * q4 + 2], vv[4 * q4 + 3]);

    int jl[E + 1];
    {
        const int4* ip = reinterpret_cast<const int4*>(idx + k0);
        #pragma unroll
        for (int q4 = 0; q4 < E / 4; ++q4) {
            int4 t4 = ip[q4];
            jl[4 * q4] = t4.x; jl[4 * q4 + 1] = t4.y;
            jl[4 * q4 + 2] = t4.z; jl[4 * q4 + 3] = t4.w;
        }
        jl[E] = (k0 + E < K) ? idx[k0 + E] : n;
    }

    float* wb = w_out + (size_t)b * m;
    float* rb = r_out + (size_t)b * m;
    float phi_acc = 0.f;

    if (staged) {
        if (tid == CGBLK - 1)
            sVN = last ? 0.f : payload(poll_tag(LINE(0, blk + 1) + PW_V0, FG));
        #pragma unroll
        for (int q = 0; q < E; ++q) sX[PAD(jl[q] - lo)] = vv[q];
        __syncthreads();
        int tLo = jloB - lo;
        int wrHi = (jhiB < m) ? jhiB : m;
        int tHi = wrHi - lo;
        float vnext = sVN;
        for (int t = tLo + tid; t < tHi; t += CGBLK) {
            int i = lo + t;
            float s_cur = sX[PAD(t)];
            float s_next = (i + 1 == jhiB) ? vnext : sX[PAD(t + 1)];
            float w = sW[PAD(t)];
            float rv = s_next - s_cur;
            wb[i] = w;
            rb[i] = rv;
            phi_acc += w * w * rv * rv;
        }
    } else {
        // fallback (span > SPAN_MAX; ~improbable): serial walk on global
        sEa[tid] = vv[0];
        __syncthreads();
        float v_next = 0.f;
        if (tid < CGBLK - 1)      v_next = sEa[tid + 1];
        else if (!last)           v_next = payload(poll_tag(LINE(0, blk + 1) + PW_V0, FG));
        const bool first_thread = first && (tid == 0);
        const bool last_thread  = last && (tid == CGBLK - 1);
        int j_lo = first_thread ? 0 : jl[0];
        int j_hi = last_thread ? n : jl[E];
        int kptr = 0;
        int i = j_lo;
        float s_cur;
        if (kptr < E && i == jl[kptr]) { s_cur = vv[kptr]; ++kptr; }
        else s_cur = nn(xb[i]);
        while (i < j_hi) {
            int ip = i + 1;
            float s_next;
            if (ip == j_hi) s_next = v_next;
            else if (kptr < E && ip == jl[kptr]) { s_next = vv[kptr]; ++kptr; }
            else s_next = nn(xb[ip]);
            if (i < m) {
                float wv = sp_w(ub[i]);
                float rv = s_next - s_cur;
                wb[i] = wv;
                rb[i] = rv;
                phi_acc += wv * wv * rv * rv;
            }
            s_cur = s_next;
            i = ip;
        }
    }

    // phi: one tagged all-to-all; batch leader single writer
    float pblk = blockReduceSum(phi_acc);
    if (tid == 0) sys_st64(LINE(0, blk) + PW_PHI, mkword(FG, pblk));
    if (first) {
        int lane = tid & 63, wid = tid >> 6;
        if (wid == 0) {
            float pv = 0.f;
            if (lane < bpb)
                pv = payload(poll_tag(LINE(0, bbase + lane) + PW_PHI, FG));
            #pragma unroll
            for (int off = 16; off > 0; off >>= 1) pv += __shfl_down(pv, off, 32);
            if (lane == 0) phi[b] = pv;
        }
    }
}

extern "C" void kernel_launch(void* const* d_in, const int* in_sizes, int n_in,
                              void* d_out, int out_size, void* d_ws, size_t ws_size,
                              hipStream_t stream) {
    const float* u  = (const float*)d_in[0];  // [B, n-1]
    const float* x  = (const float*)d_in[1];  // [B, n]
    const int* idx  = (const int*)d_in[2];    // [K], sorted

    const int B = 16;
    const int n = in_sizes[1] / B;   // 262144
    const int m = n - 1;             // 262143
    const int K = in_sizes[2];       // 131072
    const int NK = B * K;            // 2097152
    const int GRID = NK / CHUNK;     // 512 blocks = 2 per CU

    float* out   = (float*)d_out;
    float* phi   = out;                         // [B]
    float* v_out = out + B;                     // [B,K]
    float* r_out = v_out + (size_t)B * K;       // [B,m]
    float* w_out = r_out + (size_t)B * m;       // [B,m]

    (void)m;
    char* ws = (char*)d_ws;
    unsigned long long* slot = (unsigned long long*)ws;
    size_t slot_words = (size_t)2 * GRID * SLOT_STRIDE;   // 1MB

    hipMemsetAsync(slot, 0, sizeof(unsigned long long) * slot_words, stream);

    k_cg_pers<<<GRID, CGBLK, 0, stream>>>(idx, u, x, v_out, w_out, r_out, phi,
                                          slot, n, K, B, GRID);
}

// Round 18
// 119.411 us; speedup vs baseline: 1.2641x; 1.0290x over previous
//
#include <hip/hip_runtime.h>
#include <math.h>

#define MAX_ITER 20
#define EPS_W 1e-3f
#define CLAMP_MIN 1e-4f
#define CLAMP_MAX 1e4f

#define E 16
#define CGBLK 256
#define CHUNK (E * CGBLK)  // 4096 elems/block; bpb = K/CHUNK = 32
#define SPAN_MAX 9216
#define PAD(t) ((t) + ((t) >> 5))
#define SPAN_PAD (SPAN_MAX + SPAN_MAX / 32)  // 9504

// Per-block 1KB slot line, every word self-tagged {gen|payload} (one-hop).
#define SLOT_STRIDE 128
#define W_D1 0
#define W_D2 1
#define W_RS0 2
#define W_EL 3   // left-edge (kp[0]; r[0] at init on parity 1)
#define W_ER 4   // right-edge
#define W_V0 5
#define W_PHI 6
#define W_XCC 8  // verification: this block's XCC_ID (system scope)
#define W_GRP 9  // verification: leader verdict (system scope)

__device__ __forceinline__ float sp_w(float u) {
    float sp = fmaxf(u, 0.f) + log1pf(expf(-fabsf(u)));
    float w = sp + EPS_W;
    return fminf(fmaxf(w, CLAMP_MIN), CLAMP_MAX);
}
__device__ __forceinline__ float nn(float x) { return (x == x) ? x : 0.f; }

// Scope-selectable atomics. SYSTEM = cache-bypassing UC (cross-XCD correct,
// ~1.7us/hop). AGENT = sc0 (L1-bypass, shared per-XCD L2, ~0.1-0.2us) — only
// valid when all communicating blocks are verified co-resident on one XCD.
__device__ __forceinline__ unsigned long long uld64(const unsigned long long* p, bool ag) {
    return ag ? __hip_atomic_load(p, __ATOMIC_RELAXED, __HIP_MEMORY_SCOPE_AGENT)
              : __hip_atomic_load(p, __ATOMIC_RELAXED, __HIP_MEMORY_SCOPE_SYSTEM);
}
__device__ __forceinline__ unsigned long long uld64_acq(const unsigned long long* p, bool ag) {
    return ag ? __hip_atomic_load(p, __ATOMIC_ACQUIRE, __HIP_MEMORY_SCOPE_AGENT)
              : __hip_atomic_load(p, __ATOMIC_ACQUIRE, __HIP_MEMORY_SCOPE_SYSTEM);
}
__device__ __forceinline__ void ust64(unsigned long long* p, unsigned long long v, bool ag) {
    if (ag) __hip_atomic_store(p, v, __ATOMIC_RELAXED, __HIP_MEMORY_SCOPE_AGENT);
    else    __hip_atomic_store(p, v, __ATOMIC_RELAXED, __HIP_MEMORY_SCOPE_SYSTEM);
}
__device__ __forceinline__ void sys_st64(unsigned long long* p, unsigned long long v) {
    __hip_atomic_store(p, v, __ATOMIC_RELAXED, __HIP_MEMORY_SCOPE_SYSTEM);
}
__device__ __forceinline__ unsigned long long poll_tag(const unsigned long long* p,
                                                       unsigned gen, bool ag) {
    unsigned long long v; int s = 0;
    for (;;) {
        v = uld64(p, ag);
        if ((unsigned)(v >> 32) >= gen) return v;
        if ((++s & 63) == 0) {
            v = uld64_acq(p, ag);
            if ((unsigned)(v >> 32) >= gen) return v;
        }
        __builtin_amdgcn_s_sleep(1);
    }
}
__device__ __forceinline__ unsigned long long poll_tag_sys(const unsigned long long* p,
                                                           unsigned gen) {
    return poll_tag(p, gen, false);
}
__device__ __forceinline__ unsigned long long mkword(unsigned gen, float f) {
    return ((unsigned long long)gen << 32) | (unsigned long long)__float_as_uint(f);
}
__device__ __forceinline__ float payload(unsigned long long v) { return __uint_as_float((unsigned)v); }

// valid on tid 0 only; block = 256 threads (4 waves)
__device__ __forceinline__ float blockReduceSum(float v) {
    #pragma unroll
    for (int off = 32; off > 0; off >>= 1) v += __shfl_down(v, off, 64);
    __shared__ float smem[4];
    int lane = threadIdx.x & 63, wid = threadIdx.x >> 6;
    if (lane == 0) smem[wid] = v;
    __syncthreads();
    float r = 0.f;
    if (threadIdx.x == 0) r = smem[0] + smem[1] + smem[2] + smem[3];
    return r;
}
// paired reduction; valid on tid 0 only
__device__ __forceinline__ float2 blockReduceSum2(float a, float b) {
    #pragma unroll
    for (int off = 32; off > 0; off >>= 1) {
        a += __shfl_down(a, off, 64);
        b += __shfl_down(b, off, 64);
    }
    __shared__ float sa[4], sb[4];
    int lane = threadIdx.x & 63, wid = threadIdx.x >> 6;
    if (lane == 0) { sa[wid] = a; sb[wid] = b; }
    __syncthreads();
    float ra = 0.f, rb = 0.f;
    if (threadIdx.x == 0) {
        ra = sa[0] + sa[1] + sa[2] + sa[3];
        rb = sb[0] + sb[1] + sb[2] + sb[3];
    }
    return make_float2(ra, rb);
}

// Plain-CG persistent kernel (r14 structure, best = 108.7us) + XCD-local
// batch mapping with runtime-verified agent-scope fast path.
// Plain launch; co-residency by capacity: waves_per_eu(2,2) + 78KB LDS ->
// 2 blocks/CU, grid 512 = 2 x 256 CU (spin rounds proven r5-r17).
__global__ __attribute__((amdgpu_flat_work_group_size(256, 256),
                          amdgpu_waves_per_eu(2, 2)))
void k_cg_pers(const int* __restrict__ idx, const float* __restrict__ u_all,
               const float* __restrict__ x, float* __restrict__ v_out,
               float* __restrict__ w_out, float* __restrict__ r_out,
               float* __restrict__ phi,
               unsigned long long* __restrict__ slot,   // [2][nblk][SLOT_STRIDE]
               int n, int K, int B, int nblk) {
    const int blk = blockIdx.x, tid = threadIdx.x;
    const int bpb = K / CHUNK;                  // 32
    // XCD-local remap: members of a batch share blk&7 (same XCD if round-robin).
    const bool remap_ok = (nblk == 512) && (bpb == 32) && (B == 16);
    int vb, b;
    if (remap_ok) {
        int xcd = blk & 7, sl = blk >> 3;
        vb = sl & 31;
        b  = xcd * 2 + (sl >> 5);
    } else { vb = blk % bpb; b = blk / bpb; }
    const int lb = b * bpb + vb;                // logical line index
    const int lbbase = b * bpb;
    const bool first = (vb == 0), last = (vb == bpb - 1);
    const int k0 = vb * CHUNK + tid * E;
    const int m = n - 1;
    const float* ub = u_all + (size_t)b * m;
    const float* xb = x + (size_t)b * n;

    auto SL = [&](int par, int lb_, int w) -> unsigned long long* {
        return slot + ((size_t)par * nblk + lb_) * SLOT_STRIDE + w;
    };

    // publish this block's XCC_ID early (system scope; tag 1)
    {
        unsigned xcc = __builtin_amdgcn_s_getreg((3 << 11) | 20) & 0xfu;  // HW_REG_XCC_ID
        if (tid == 0) sys_st64(SL(0, lb, W_XCC), (1ull << 32) | xcc);
    }

    __shared__ float sX[SPAN_PAD], sW[SPAN_PAD];
    __shared__ float sLa[CGBLK], sRa[CGBLK];
    __shared__ float sm[3];
    __shared__ int sInfo[4];
    __shared__ float sVN;
    __shared__ int sAg;

    // ---- block i-span + coalesced staging ----
    if (tid == 0) {
        int kblk = vb * CHUNK;
        int jlo = first ? 0 : idx[kblk];
        int jhi = last ? n : idx[kblk + CHUNK];
        int lo_ = (jlo > 0) ? jlo - 1 : 0;
        sInfo[0] = lo_; sInfo[1] = jhi - lo_; sInfo[2] = jlo; sInfo[3] = jhi;
    }
    __syncthreads();
    const int lo = sInfo[0], len = sInfo[1], jloB = sInfo[2], jhiB = sInfo[3];
    const bool staged = (len <= SPAN_MAX);
    if (staged) {
        for (int t = tid; t < len; t += CGBLK) {
            int i = lo + t;
            sX[PAD(t)] = nn(xb[i]);
            sW[PAD(t)] = (i < m) ? sp_w(ub[i]) : 0.f;
        }
        __syncthreads();
    }
    auto LXn = [&](int i) -> float { return staged ? sX[PAD(i - lo)] : nn(xb[i]); };
    auto LW  = [&](int i) -> float { return staged ? sW[PAD(i - lo)] : sp_w(ub[i]); };

    // ---- co-location verification (system scope) ----
    {
        int lane = tid & 63, wid = tid >> 6;
        if (vb == 0 && wid == 0) {
            int val = 0;
            if (lane < bpb)
                val = (int)((unsigned)poll_tag_sys(SL(0, lbbase + lane, W_XCC), 1u) & 0xfu);
            int mn = val, mx = val;
            #pragma unroll
            for (int off = 16; off > 0; off >>= 1) {
                int a = __shfl_down(mn, off, 32), c = __shfl_down(mx, off, 32);
                mn = (a < mn) ? a : mn; mx = (c > mx) ? c : mx;
            }
            if (lane == 0) {
                unsigned uni = (mn == mx) ? 1u : 0u;
                sys_st64(SL(0, lb, W_GRP), (2ull << 32) | (uni << 8) | ((unsigned)mn & 0xfu));
            }
        }
        if (wid == 1 && lane < B) {
            unsigned long long v = poll_tag_sys(SL(0, lane * bpb, W_GRP), 2u);
            int uni = (int)(((unsigned)v >> 8) & 1u);
            int val = (int)((unsigned)v & 0xfu);
            int mn = val, mx = val, au = uni;
            #pragma unroll
            for (int off = 8; off > 0; off >>= 1) {
                int a = __shfl_down(mn, off, 16), c = __shfl_down(mx, off, 16);
                int d = __shfl_down(au, off, 16);
                mn = (a < mn) ? a : mn; mx = (c > mx) ? c : mx; au &= d;
            }
            if (lane == 0) sAg = (au && (mn != mx)) ? 1 : 0;
        }
        __syncthreads();
    }
    const bool AG = remap_ok && (sAg != 0);

    // ---- init: dg, cl, r0 in registers (padded-LDS gathers) ----
    int jj[E + 2];
    {
        const int4* ip = reinterpret_cast<const int4*>(idx + k0);
        #pragma unroll
        for (int q4 = 0; q4 < E / 4; ++q4) {
            int4 t4 = ip[q4];
            jj[1 + 4 * q4] = t4.x; jj[2 + 4 * q4] = t4.y;
            jj[3 + 4 * q4] = t4.z; jj[4 + 4 * q4] = t4.w;
        }
        jj[0]     = (k0 > 0)     ? idx[k0 - 1] : -1000000;
        jj[E + 1] = (k0 + E < K) ? idx[k0 + E] : -1000000;
    }
    float vv[E], r[E], p[E], kp[E], dgr[E], clr[E + 1];
    float s0 = 0.f;
    #pragma unroll
    for (int q = 0; q < E; ++q) {
        int j = jj[q + 1];
        bool la = (jj[q] == j - 1);
        bool ra = (jj[q + 2] == j + 1);
        float wl = 0.f, wr = 0.f;
        if (j >= 1)     { float w = LW(j - 1); wl = w * w; }
        if (j <= n - 2) { float w = LW(j);     wr = w * w; }
        float rhs = 0.f;
        if (j >= 1 && !la)     rhs += wl * LXn(j - 1);
        if (j <= n - 2 && !ra) rhs += wr * LXn(j + 1);
        vv[q] = 0.f; r[q] = rhs; p[q] = 0.f; kp[q] = 0.f;
        dgr[q] = wl + wr;
        clr[q] = la ? wl : 0.f;
        s0 += rhs * rhs;
    }
    {
        float cl8 = 0.f;
        int j8 = jj[E + 1];
        if ((k0 + E) < K && jj[E] == j8 - 1) { float w = LW(j8 - 1); cl8 = w * w; }
        clr[E] = cl8;
    }
    // publish initial r-edges (tag 1, parity-1 line)
    if (tid == 0)         ust64(SL(1, lb, W_EL), mkword(1u, r[0]), AG);
    if (tid == CGBLK - 1) ust64(SL(1, lb, W_ER), mkword(1u, r[E - 1]), AG);

    float s0b = blockReduceSum(s0);

    float rs = 0.f, beta = 0.f;
    float r_nbL = 0.f, p_nbL = 0.f;   // live in tid 0
    float r_nbR = 0.f, p_nbR = 0.f;   // live in tid 255

    for (int it = 0; it < MAX_ITER; ++it) {
        const unsigned G = (unsigned)(it + 2);
        const int par = it & 1;
        if (it == 0) {
            if (tid == 0 && !first)
                r_nbL = payload(poll_tag(SL(1, lb - 1, W_ER), 1u, AG));
            if (tid == CGBLK - 1 && !last)
                r_nbR = payload(poll_tag(SL(1, lb + 1, W_EL), 1u, AG));
        }
        #pragma unroll
        for (int q = 0; q < E; ++q) p[q] = r[q] + beta * p[q];
        if (tid == 0)         p_nbL = r_nbL + beta * p_nbL;
        if (tid == CGBLK - 1) p_nbR = r_nbR + beta * p_nbR;
        sLa[tid] = p[0]; sRa[tid] = p[E - 1];
        __syncthreads();
        float pl = (tid > 0) ? sRa[tid - 1] : (first ? 0.f : p_nbL);
        float pr = (tid < CGBLK - 1) ? sLa[tid + 1] : (last ? 0.f : p_nbR);
        float d1 = 0.f, d2 = 0.f;
        #pragma unroll
        for (int q = 0; q < E; ++q) {
            float pm = (q == 0) ? pl : p[q - 1];
            float pp = (q == E - 1) ? pr : p[q + 1];
            kp[q] = dgr[q] * p[q] - clr[q] * pm - clr[q + 1] * pp;
            d1 += p[q] * kp[q];
            d2 += kp[q] * kp[q];
        }
        if (tid == 0)         ust64(SL(par, lb, W_EL), mkword(G, kp[0]), AG);
        if (tid == CGBLK - 1) ust64(SL(par, lb, W_ER), mkword(G, kp[E - 1]), AG);
        float2 db = blockReduceSum2(d1, d2);
        if (tid == 0) {
            ust64(SL(par, lb, W_D1), mkword(G, db.x), AG);
            ust64(SL(par, lb, W_D2), mkword(G, db.y), AG);
            if (it == 0) ust64(SL(0, lb, W_RS0), mkword(G, s0b), AG);
        }
        // ---- one-hop all-to-all poll ----
        float kpnbl = 0.f, kpnbr = 0.f;
        {
            int lane = tid & 63, wid = tid >> 6;
            if (wid == 0) {
                int which = (lane >> 5) ? W_D2 : W_D1;
                int li = lane & 31;
                float pv = 0.f;
                if (li < bpb)
                    pv = payload(poll_tag(SL(par, lbbase + li, which), G, AG));
                #pragma unroll
                for (int off = 16; off > 0; off >>= 1) pv += __shfl_down(pv, off, 32);
                if (lane == 0)  sm[0] = pv;
                if (lane == 32) sm[1] = pv;
            } else if (wid == 1 && it == 0 && lane < 32) {
                float pv = 0.f;
                if (lane < bpb)
                    pv = payload(poll_tag(SL(0, lbbase + lane, W_RS0), 2u, AG));
                #pragma unroll
                for (int off = 16; off > 0; off >>= 1) pv += __shfl_down(pv, off, 32);
                if (lane == 0) sm[2] = pv;
            }
            if (tid == 0 && !first)
                kpnbl = payload(poll_tag(SL(par, lb - 1, W_ER), G, AG));
            if (tid == CGBLK - 1 && !last)
                kpnbr = payload(poll_tag(SL(par, lb + 1, W_EL), G, AG));
        }
        __syncthreads();
        float D1 = sm[0], D2 = sm[1];
        if (it == 0) rs = sm[2];
        float alpha = rs / (D1 + 1e-30f);
        float rs_new = fmaxf(alpha * alpha * D2 - rs, 0.f);
        #pragma unroll
        for (int q = 0; q < E; ++q) {
            vv[q] += alpha * p[q];
            r[q]  -= alpha * kp[q];
        }
        if (tid == 0 && !first)        r_nbL -= alpha * kpnbl;
        if (tid == CGBLK - 1 && !last) r_nbR -= alpha * kpnbr;
        beta = rs_new / (rs + 1e-30f);
        rs = rs_new;
    }

    // ---- publish v0 early; v writeout (coalesced) ----
    const unsigned FG = (unsigned)(MAX_ITER + 2);   // 22
    if (tid == 0) ust64(SL(0, lb, W_V0), mkword(FG, vv[0]), AG);
    float* vb_out = v_out + (size_t)b * K + (size_t)vb * CHUNK + (size_t)tid * E;
    #pragma unroll
    for (int q4 = 0; q4 < E / 4; ++q4)
        reinterpret_cast<float4*>(vb_out)[q4] =
            make_float4(vv[4 * q4], vv[4 * q4 + 1], vv[4 * q4 + 2], vv[4 * q4 + 3]);

    int jl[E + 1];
    {
        const int4* ip = reinterpret_cast<const int4*>(idx + k0);
        #pragma unroll
        for (int q4 = 0; q4 < E / 4; ++q4) {
            int4 t4 = ip[q4];
            jl[4 * q4] = t4.x; jl[4 * q4 + 1] = t4.y;
            jl[4 * q4 + 2] = t4.z; jl[4 * q4 + 3] = t4.w;
        }
        jl[E] = (k0 + E < K) ? idx[k0 + E] : n;
    }

    float* wb = w_out + (size_t)b * m;
    float* rb = r_out + (size_t)b * m;
    float phi_acc = 0.f;

    if (staged) {
        if (tid == CGBLK - 1)
            sVN = last ? 0.f : payload(poll_tag(SL(0, lb + 1, W_V0), FG, AG));
        #pragma unroll
        for (int q = 0; q < E; ++q) sX[PAD(jl[q] - lo)] = vv[q];
        __syncthreads();
        int tLo = jloB - lo;
        int wrHi = (jhiB < m) ? jhiB : m;
        int tHi = wrHi - lo;
        float vnext = sVN;
        for (int t = tLo + tid; t < tHi; t += CGBLK) {
            int i = lo + t;
            float s_cur = sX[PAD(t)];
            float s_next = (i + 1 == jhiB) ? vnext : sX[PAD(t + 1)];
            float w = sW[PAD(t)];
            float rv = s_next - s_cur;
            wb[i] = w;
            rb[i] = rv;
            phi_acc += w * w * rv * rv;
        }
    } else {
        // fallback (span > SPAN_MAX, ~impossible): serial walk on global
        sLa[tid] = vv[0];
        __syncthreads();
        float v_next = 0.f;
        if (tid < CGBLK - 1)      v_next = sLa[tid + 1];
        else if (!last)           v_next = payload(poll_tag(SL(0, lb + 1, W_V0), FG, AG));
        const bool first_thread = first && (tid == 0);
        const bool last_thread  = last && (tid == CGBLK - 1);
        int j_lo = first_thread ? 0 : jl[0];
        int j_hi = last_thread ? n : jl[E];
        int kptr = 0;
        int i = j_lo;
        float s_cur;
        if (kptr < E && i == jl[kptr]) { s_cur = vv[kptr]; ++kptr; }
        else s_cur = nn(xb[i]);
        while (i < j_hi) {
            int ip = i + 1;
            float s_next;
            if (ip == j_hi) s_next = v_next;
            else if (kptr < E && ip == jl[kptr]) { s_next = vv[kptr]; ++kptr; }
            else s_next = nn(xb[ip]);
            if (i < m) {
                float wv = sp_w(ub[i]);
                float rv = s_next - s_cur;
                wb[i] = wv;
                rb[i] = rv;
                phi_acc += wv * wv * rv * rv;
            }
            s_cur = s_next;
            i = ip;
        }
    }

    // phi: one tagged all-to-all round; batch leader single writer
    float pblk = blockReduceSum(phi_acc);
    if (tid == 0) ust64(SL(0, lb, W_PHI), mkword(FG, pblk), AG);
    if (first) {
        int lane = tid & 63, wid = tid >> 6;
        if (wid == 0) {
            float pv = 0.f;
            if (lane < bpb)
                pv = payload(poll_tag(SL(0, lbbase + lane, W_PHI), FG, AG));
            #pragma unroll
            for (int off = 16; off > 0; off >>= 1) pv += __shfl_down(pv, off, 32);
            if (lane == 0) phi[b] = pv;
        }
    }
}

extern "C" void kernel_launch(void* const* d_in, const int* in_sizes, int n_in,
                              void* d_out, int out_size, void* d_ws, size_t ws_size,
                              hipStream_t stream) {
    const float* u  = (const float*)d_in[0];  // [B, n-1]
    const float* x  = (const float*)d_in[1];  // [B, n]
    const int* idx  = (const int*)d_in[2];    // [K], sorted

    const int B = 16;
    const int n = in_sizes[1] / B;   // 262144
    const int m = n - 1;             // 262143
    const int K = in_sizes[2];       // 131072
    const int NK = B * K;            // 2097152
    const int GRID = NK / CHUNK;     // 512 blocks = 2 per CU

    float* out   = (float*)d_out;
    float* phi   = out;                         // [B]
    float* v_out = out + B;                     // [B,K]
    float* r_out = v_out + (size_t)B * K;       // [B,m]
    float* w_out = r_out + (size_t)B * m;       // [B,m]

    char* ws = (char*)d_ws;
    unsigned long long* slot = (unsigned long long*)ws;
    size_t slot_words = (size_t)2 * GRID * SLOT_STRIDE;   // 1MB

    // zero the slot region each call (tags restart every replay)
    hipMemsetAsync(slot, 0, sizeof(unsigned long long) * slot_words, stream);

    k_cg_pers<<<GRID, 256, 0, stream>>>(idx, u, x, v_out, w_out, r_out, phi,
                                        slot, n, K, B, GRID);
}

// Round 19
// 109.535 us; speedup vs baseline: 1.3781x; 1.0902x over previous
//
#include <hip/hip_runtime.h>
#include <math.h>

#define MAX_ITER 20
#define EPS_W 1e-3f
#define CLAMP_MIN 1e-4f
#define CLAMP_MAX 1e4f

#define E 16
#define CGBLK 256
#define CHUNK (E * CGBLK)  // 4096 elems/block; bpb = K/CHUNK = 32
#define SPAN_MAX 9216      // block i-span bound (mean 8193, sd ~64; 16 sigma)
#define PAD(t) ((t) + ((t) >> 5))   // +1-per-32 padding: kills stride-32 bank conflicts
#define SPAN_PAD (SPAN_MAX + SPAN_MAX / 32)  // 9504

// Per-block slot line: 128 u64 = 1KB; each block's published words live on a
// private interleave-aligned line. Every word is self-tagged {gen|payload} ->
// one fabric hop per round (~3.4us, the measured cross-XCD floor).
#define SLOT_STRIDE 128
#define W_D1 0
#define W_D2 1
#define W_RS0 2
#define W_EL 3   // left-edge value (kp[0]; r[0] at init on parity 1)
#define W_ER 4   // right-edge value (kp[E-1]; r[E-1] at init on parity 1)
#define W_V0 5   // epilogue: block's first v
#define W_PHI 6  // epilogue: block phi partial

__device__ __forceinline__ float sp_w(float u) {
    float sp = fmaxf(u, 0.f) + log1pf(expf(-fabsf(u)));
    float w = sp + EPS_W;
    return fminf(fmaxf(w, CLAMP_MIN), CLAMP_MAX);
}
__device__ __forceinline__ float nn(float x) { return (x == x) ? x : 0.f; }

// SYSTEM-scope relaxed atomics: cache-bypassing, coherence-point direct.
// (r6->r7: poll rounds 21us -> 3.4us. Agent scope re-hits stale L1 — r18.)
__device__ __forceinline__ unsigned long long sys_ld64(const unsigned long long* p) {
    return __hip_atomic_load(p, __ATOMIC_RELAXED, __HIP_MEMORY_SCOPE_SYSTEM);
}
__device__ __forceinline__ unsigned long long sys_ld64_acq(const unsigned long long* p) {
    return __hip_atomic_load(p, __ATOMIC_ACQUIRE, __HIP_MEMORY_SCOPE_SYSTEM);
}
__device__ __forceinline__ void sys_st64(unsigned long long* p, unsigned long long v) {
    __hip_atomic_store(p, v, __ATOMIC_RELAXED, __HIP_MEMORY_SCOPE_SYSTEM);
}
__device__ __forceinline__ unsigned long long poll_tag(const unsigned long long* p, unsigned gen) {
    unsigned long long v; int s = 0;
    for (;;) {
        v = sys_ld64(p);
        if ((unsigned)(v >> 32) >= gen) return v;
        if ((++s & 63) == 0) {               // livelock insurance only
            v = sys_ld64_acq(p);
            if ((unsigned)(v >> 32) >= gen) return v;
        }
        __builtin_amdgcn_s_sleep(1);
    }
}
__device__ __forceinline__ unsigned long long mkword(unsigned gen, float f) {
    return ((unsigned long long)gen << 32) | (unsigned long long)__float_as_uint(f);
}
__device__ __forceinline__ float payload(unsigned long long v) {
    return __uint_as_float((unsigned)v);
}

// valid on tid 0 only; block = 256 threads (4 waves)
__device__ __forceinline__ float blockReduceSum(float v) {
    #pragma unroll
    for (int off = 32; off > 0; off >>= 1) v += __shfl_down(v, off, 64);
    __shared__ float smem[4];
    int lane = threadIdx.x & 63, wid = threadIdx.x >> 6;
    if (lane == 0) smem[wid] = v;
    __syncthreads();
    float r = 0.f;
    if (threadIdx.x == 0) r = smem[0] + smem[1] + smem[2] + smem[3];
    return r;
}
// paired reduction; valid on tid 0 only
__device__ __forceinline__ float2 blockReduceSum2(float a, float b) {
    #pragma unroll
    for (int off = 32; off > 0; off >>= 1) {
        a += __shfl_down(a, off, 64);
        b += __shfl_down(b, off, 64);
    }
    __shared__ float sa[4], sb[4];
    int lane = threadIdx.x & 63, wid = threadIdx.x >> 6;
    if (lane == 0) { sa[wid] = a; sb[wid] = b; }
    __syncthreads();
    float ra = 0.f, rb = 0.f;
    if (threadIdx.x == 0) {
        ra = sa[0] + sa[1] + sa[2] + sa[3];
        rb = sb[0] + sb[1] + sb[2] + sb[3];
    }
    return make_float2(ra, rb);
}

// Persistent single-reduction CG + fused pre/post; per-block 1KB slot lines.
// Plain launch (graph-capturable). Co-residency by capacity: waves_per_eu(2,2)
// + 78KB LDS -> exactly 2 blocks/CU, grid 512 = 2 x 256 CU (proven r5-r18).
__global__ __attribute__((amdgpu_flat_work_group_size(256, 256),
                          amdgpu_waves_per_eu(2, 2)))
void k_cg_pers(const int* __restrict__ idx, const float* __restrict__ u_all,
               const float* __restrict__ x, float* __restrict__ v_out,
               float* __restrict__ w_out, float* __restrict__ r_out,
               float* __restrict__ phi,
               unsigned long long* __restrict__ slot,   // [2][nblk][SLOT_STRIDE]
               int n, int K, int B, int nblk) {
    const int blk = blockIdx.x, tid = threadIdx.x;
    const int bpb = K / CHUNK;                  // 32
    const int b = blk / bpb, bbase = b * bpb;
    const bool first = (blk == bbase), last = (blk == bbase + bpb - 1);
    const int k0 = (blk - bbase) * CHUNK + tid * E;
    const int m = n - 1;
    const float* ub = u_all + (size_t)b * m;
    const float* xb = x + (size_t)b * n;

    auto SL = [&](int par, int blk_, int w) -> unsigned long long* {
        return slot + ((size_t)par * nblk + blk_) * SLOT_STRIDE + w;
    };

    __shared__ float sX[SPAN_PAD], sW[SPAN_PAD];
    __shared__ float sLa[CGBLK], sRa[CGBLK];
    __shared__ float sm[3];           // D1, D2, RS0
    __shared__ int sInfo[4];          // lo, len, jloB, jhiB
    __shared__ float sVN;             // next block's first v

    // ---- block i-span + coalesced staging: sX = nn(x), sW = sp_w(u) ----
    if (tid == 0) {
        int kblk = (blk - bbase) * CHUNK;
        int jlo = first ? 0 : idx[kblk];
        int jhi = last ? n : idx[kblk + CHUNK];
        int lo_ = (jlo > 0) ? jlo - 1 : 0;
        sInfo[0] = lo_;
        sInfo[1] = jhi - lo_;
        sInfo[2] = jlo;
        sInfo[3] = jhi;
    }
    __syncthreads();
    const int lo = sInfo[0], len = sInfo[1], jloB = sInfo[2], jhiB = sInfo[3];
    const bool staged = (len <= SPAN_MAX);
    if (staged) {
        for (int t = tid; t < len; t += CGBLK) {
            int i = lo + t;
            sX[PAD(t)] = nn(xb[i]);
            sW[PAD(t)] = (i < m) ? sp_w(ub[i]) : 0.f;
        }
        __syncthreads();
    }
    auto LXn = [&](int i) -> float { return staged ? sX[PAD(i - lo)] : nn(xb[i]); };
    auto LW  = [&](int i) -> float { return staged ? sW[PAD(i - lo)] : sp_w(ub[i]); };

    // ---- init: dg, cl, r0 in registers (LDS gathers, conflict-reduced) ----
    int jj[E + 2];
    {
        const int4* ip = reinterpret_cast<const int4*>(idx + k0);  // k0 % 16 == 0
        #pragma unroll
        for (int q4 = 0; q4 < E / 4; ++q4) {
            int4 t = ip[q4];
            jj[1 + 4 * q4] = t.x; jj[2 + 4 * q4] = t.y;
            jj[3 + 4 * q4] = t.z; jj[4 + 4 * q4] = t.w;
        }
        jj[0]     = (k0 > 0)      ? idx[k0 - 1] : -1000000;
        jj[E + 1] = (k0 + E < K)  ? idx[k0 + E] : -1000000;
    }
    float vv[E], r[E], p[E], kp[E], dgr[E], clr[E + 1];
    float s0 = 0.f;
    #pragma unroll
    for (int q = 0; q < E; ++q) {
        int j = jj[q + 1];
        bool la = (jj[q] == j - 1);
        bool ra = (jj[q + 2] == j + 1);
        float wl = 0.f, wr = 0.f;
        if (j >= 1)     { float w = LW(j - 1); wl = w * w; }
        if (j <= n - 2) { float w = LW(j);     wr = w * w; }
        float rhs = 0.f;
        if (j >= 1 && !la)     rhs += wl * LXn(j - 1);
        if (j <= n - 2 && !ra) rhs += wr * LXn(j + 1);
        vv[q] = 0.f; r[q] = rhs; p[q] = 0.f; kp[q] = 0.f;
        dgr[q] = wl + wr;
        clr[q] = la ? wl : 0.f;
        s0 += rhs * rhs;
    }
    {
        float cl8 = 0.f;
        int j8 = jj[E + 1];
        if ((k0 + E) < K && jj[E] == j8 - 1) { float w = LW(j8 - 1); cl8 = w * w; }
        clr[E] = cl8;
    }
    // publish initial r-edges (tag 1, parity-1 line words EL/ER)
    if (tid == 0)         sys_st64(SL(1, blk, W_EL), mkword(1u, r[0]));
    if (tid == CGBLK - 1) sys_st64(SL(1, blk, W_ER), mkword(1u, r[E - 1]));

    float s0b = blockReduceSum(s0);   // tid0; published with round 0

    float rs = 0.f, beta = 0.f;
    float r_nbL = 0.f, p_nbL = 0.f;   // live in tid 0
    float r_nbR = 0.f, p_nbR = 0.f;   // live in tid 255

    for (int it = 0; it < MAX_ITER; ++it) {
        const unsigned G = (unsigned)(it + 2);
        const int par = it & 1;
        if (it == 0) {   // fetch neighbor r0 edges (self-tagged)
            if (tid == 0 && !first)
                r_nbL = payload(poll_tag(SL(1, blk - 1, W_ER), 1u));
            if (tid == CGBLK - 1 && !last)
                r_nbR = payload(poll_tag(SL(1, blk + 1, W_EL), 1u));
        }
        // p update (beta=0 at it=0) + bitwise neighbor mirror
        #pragma unroll
        for (int q = 0; q < E; ++q) p[q] = r[q] + beta * p[q];
        if (tid == 0)         p_nbL = r_nbL + beta * p_nbL;
        if (tid == CGBLK - 1) p_nbR = r_nbR + beta * p_nbR;
        sLa[tid] = p[0]; sRa[tid] = p[E - 1];
        __syncthreads();
        float pl = (tid > 0) ? sRa[tid - 1] : (first ? 0.f : p_nbL);
        float pr = (tid < CGBLK - 1) ? sLa[tid + 1] : (last ? 0.f : p_nbR);
        float d1 = 0.f, d2 = 0.f;
        #pragma unroll
        for (int q = 0; q < E; ++q) {
            float pm = (q == 0) ? pl : p[q - 1];
            float pp = (q == E - 1) ? pr : p[q + 1];
            kp[q] = dgr[q] * p[q] - clr[q] * pm - clr[q + 1] * pp;
            d1 += p[q] * kp[q];
            d2 += kp[q] * kp[q];
        }
        // publish Kp edges early (gen-tagged, parity-buffered, own line)
        if (tid == 0)         sys_st64(SL(par, blk, W_EL), mkword(G, kp[0]));
        if (tid == CGBLK - 1) sys_st64(SL(par, blk, W_ER), mkword(G, kp[E - 1]));
        float2 db = blockReduceSum2(d1, d2);
        if (tid == 0) {
            sys_st64(SL(par, blk, W_D1), mkword(G, db.x));
            sys_st64(SL(par, blk, W_D2), mkword(G, db.y));
            if (it == 0) sys_st64(SL(0, blk, W_RS0), mkword(G, s0b));
        }
        // ---- all-to-all poll: one fabric hop, 32 distinct lines ----
        float kpnbl = 0.f, kpnbr = 0.f;
        {
            int lane = tid & 63, wid = tid >> 6;
            if (wid == 0) {
                int which = (lane >> 5) ? W_D2 : W_D1;
                int li = lane & 31;
                float pv = 0.f;
                if (li < bpb)
                    pv = payload(poll_tag(SL(par, bbase + li, which), G));
                #pragma unroll
                for (int off = 16; off > 0; off >>= 1) pv += __shfl_down(pv, off, 32);
                if (lane == 0)  sm[0] = pv;
                if (lane == 32) sm[1] = pv;
            } else if (wid == 1 && it == 0 && lane < 32) {
                float pv = 0.f;
                if (lane < bpb)
                    pv = payload(poll_tag(SL(0, bbase + lane, W_RS0), 2u));
                #pragma unroll
                for (int off = 16; off > 0; off >>= 1) pv += __shfl_down(pv, off, 32);
                if (lane == 0) sm[2] = pv;
            }
            if (tid == 0 && !first)
                kpnbl = payload(poll_tag(SL(par, blk - 1, W_ER), G));
            if (tid == CGBLK - 1 && !last)
                kpnbr = payload(poll_tag(SL(par, blk + 1, W_EL), G));
        }
        __syncthreads();
        float D1 = sm[0], D2 = sm[1];
        if (it == 0) rs = sm[2];
        float alpha = rs / (D1 + 1e-30f);
        float rs_new = fmaxf(alpha * alpha * D2 - rs, 0.f);
        #pragma unroll
        for (int q = 0; q < E; ++q) {
            vv[q] += alpha * p[q];
            r[q]  -= alpha * kp[q];
        }
        if (tid == 0 && !first)        r_nbL -= alpha * kpnbl;
        if (tid == CGBLK - 1 && !last) r_nbR -= alpha * kpnbr;
        beta = rs_new / (rs + 1e-30f);
        rs = rs_new;
    }

    // ---- publish v0 early; v writeout (coalesced) ----
    const unsigned FG = (unsigned)(MAX_ITER + 2);   // 22
    if (tid == 0) sys_st64(SL(0, blk, W_V0), mkword(FG, vv[0]));
    float* vb = v_out + (size_t)b * K + (size_t)(blk - bbase) * CHUNK + (size_t)tid * E;
    #pragma unroll
    for (int q4 = 0; q4 < E / 4; ++q4)
        reinterpret_cast<float4*>(vb)[q4] =
            make_float4(vv[4 * q4], vv[4 * q4 + 1], vv[4 * q4 + 2], vv[4 * q4 + 3]);

    // reload idx window (init's jj may have been re-used by regalloc)
    int jl[E + 1];
    {
        const int4* ip = reinterpret_cast<const int4*>(idx + k0);
        #pragma unroll
        for (int q4 = 0; q4 < E / 4; ++q4) {
            int4 t = ip[q4];
            jl[4 * q4] = t.x; jl[4 * q4 + 1] = t.y;
            jl[4 * q4 + 2] = t.z; jl[4 * q4 + 3] = t.w;
        }
        jl[E] = (k0 + E < K) ? idx[k0 + E] : n;
    }

    float* wb = w_out + (size_t)b * m;
    float* rb = r_out + (size_t)b * m;
    float phi_acc = 0.f;

    if (staged) {
        // scatter register v into padded span (padding spreads the ~32-stride)
        if (tid == CGBLK - 1)
            sVN = last ? 0.f : payload(poll_tag(SL(0, blk + 1, W_V0), FG));
        #pragma unroll
        for (int q = 0; q < E; ++q) sX[PAD(jl[q] - lo)] = vv[q];
        __syncthreads();
        // coalesced pass: r = D(s), w from sW, phi accumulate, coalesced stores
        int tLo = jloB - lo;
        int wrHi = (jhiB < m) ? jhiB : m;
        int tHi = wrHi - lo;
        float vnext = sVN;
        for (int t = tLo + tid; t < tHi; t += CGBLK) {
            int i = lo + t;
            float s_cur = sX[PAD(t)];
            float s_next = (i + 1 == jhiB) ? vnext : sX[PAD(t + 1)];
            float w = sW[PAD(t)];
            float rv = s_next - s_cur;
            wb[i] = w;
            rb[i] = rv;
            phi_acc += w * w * rv * rv;
        }
    } else {
        // fallback (len > SPAN_MAX, ~impossible): serial walk on global
        sLa[tid] = vv[0];
        __syncthreads();
        float v_next = 0.f;
        if (tid < CGBLK - 1)      v_next = sLa[tid + 1];
        else if (!last)           v_next = payload(poll_tag(SL(0, blk + 1, W_V0), FG));
        const bool first_thread = first && (tid == 0);
        const bool last_thread  = last && (tid == CGBLK - 1);
        int j_lo = first_thread ? 0 : jl[0];
        int j_hi = last_thread ? n : jl[E];
        int kptr = 0;
        int i = j_lo;
        float s_cur;
        if (kptr < E && i == jl[kptr]) { s_cur = vv[kptr]; ++kptr; }
        else s_cur = nn(xb[i]);
        while (i < j_hi) {
            int ip = i + 1;
            float s_next;
            if (ip == j_hi) s_next = v_next;
            else if (kptr < E && ip == jl[kptr]) { s_next = vv[kptr]; ++kptr; }
            else s_next = nn(xb[ip]);
            if (i < m) {
                float wv = sp_w(ub[i]);
                float rv = s_next - s_cur;
                wb[i] = wv;
                rb[i] = rv;
                phi_acc += wv * wv * rv * rv;
            }
            s_cur = s_next;
            i = ip;
        }
    }

    // phi: one tagged all-to-all round; batch leader is single writer
    float pblk = blockReduceSum(phi_acc);
    if (tid == 0) sys_st64(SL(0, blk, W_PHI), mkword(FG, pblk));
    if (first) {
        int lane = tid & 63, wid = tid >> 6;
        if (wid == 0) {
            float pv = 0.f;
            if (lane < bpb)
                pv = payload(poll_tag(SL(0, bbase + lane, W_PHI), FG));
            #pragma unroll
            for (int off = 16; off > 0; off >>= 1) pv += __shfl_down(pv, off, 32);
            if (lane == 0) phi[b] = pv;
        }
    }
}

extern "C" void kernel_launch(void* const* d_in, const int* in_sizes, int n_in,
                              void* d_out, int out_size, void* d_ws, size_t ws_size,
                              hipStream_t stream) {
    const float* u  = (const float*)d_in[0];  // [B, n-1]
    const float* x  = (const float*)d_in[1];  // [B, n]
    const int* idx  = (const int*)d_in[2];    // [K], sorted

    const int B = 16;
    const int n = in_sizes[1] / B;   // 262144
    const int m = n - 1;             // 262143
    const int K = in_sizes[2];       // 131072
    const int NK = B * K;            // 2097152
    const int GRID = NK / CHUNK;     // 512 blocks = 2 per CU

    float* out   = (float*)d_out;
    float* phi   = out;                         // [B]
    float* v_out = out + B;                     // [B,K]
    float* r_out = v_out + (size_t)B * K;       // [B,m]
    float* w_out = r_out + (size_t)B * m;       // [B,m]

    char* ws = (char*)d_ws;
    unsigned long long* slot = (unsigned long long*)ws;
    size_t slot_words = (size_t)2 * GRID * SLOT_STRIDE;   // 1MB

    // zero the slot region each call (tags restart every replay)
    hipMemsetAsync(slot, 0, sizeof(unsigned long long) * slot_words, stream);

    k_cg_pers<<<GRID, CGBLK, 0, stream>>>(idx, u, x, v_out, w_out, r_out, phi,
                                          slot, n, K, B, GRID);
}